// Round 2
// baseline (452.803 us; speedup 1.0000x reference)
//
#include <hip/hip_runtime.h>
#include <hip/hip_bf16.h>
#include <stdint.h>

// B=16, A=512, H=8, c = 512 - int(512*0.3) = 359
#define B_ 16
#define A_ 512
#define H_ 8
#define C_CROSS 359

// ---------------- threefry2x32 (exact JAX semantics) ----------------
__device__ __forceinline__ void tf2x32(uint32_t k0, uint32_t k1,
                                       uint32_t x0, uint32_t x1,
                                       uint32_t& o0, uint32_t& o1) {
  uint32_t ks2 = k0 ^ k1 ^ 0x1BD11BDAu;
  x0 += k0; x1 += k1;
#define TFR(r) { x0 += x1; x1 = (x1 << (r)) | (x1 >> (32 - (r))); x1 ^= x0; }
  TFR(13) TFR(15) TFR(26) TFR(6)   x0 += k1;  x1 += ks2 + 1u;
  TFR(17) TFR(29) TFR(16) TFR(24)  x0 += ks2; x1 += k0 + 2u;
  TFR(13) TFR(15) TFR(26) TFR(6)   x0 += k0;  x1 += k1 + 3u;
  TFR(17) TFR(29) TFR(16) TFR(24)  x0 += k1;  x1 += ks2 + 4u;
  TFR(13) TFR(15) TFR(26) TFR(6)   x0 += ks2; x1 += k0 + 5u;
#undef TFR
  o0 = x0; o1 = x1;
}

__device__ __forceinline__ float u01(uint32_t bits) {
  return __uint_as_float((bits >> 9) | 0x3f800000u) - 1.0f;
}

// PARTITIONABLE threefry (JAX >= 0.4.36 default):
//   random_bits(key,32,shape)[L] = o0 ^ o1 of tf2x32(k0,k1, hi=0, lo=L)
//   split(key,n) foldlike: child i = (o0,o1) of tf2x32(k0,k1, 0, i)
__device__ __forceinline__ float mutval(uint32_t km0, uint32_t km1, uint32_t L) {
  uint32_t a, b;
  tf2x32(km0, km1, 0u, L, a, b);
  float u = u01(a ^ b);
  return fmaxf(0.7f, u * (1.3f - 0.7f) + 0.7f);
}

// cfg layout (ints): [0]=flag(mutate?), [1]=km0, [2]=km1, [3..130]=r1[128], [131..258]=r2[128]
__global__ void rand_kernel(int* __restrict__ cfg) {
  int t = threadIdx.x;  // 128 threads
  // split(key(42),4) foldlike: child i = tf2x32(0,42, 0, i)
  uint32_t kp0, kp1, km0, km1, kr10, kr11, kr20, kr21;
  tf2x32(0u, 42u, 0u, 0u, kp0, kp1);
  tf2x32(0u, 42u, 0u, 1u, km0, km1);
  tf2x32(0u, 42u, 0u, 2u, kr10, kr11);
  tf2x32(0u, 42u, 0u, 3u, kr20, kr21);
  if (t == 0) {
    uint32_t a, b;
    tf2x32(kp0, kp1, 0u, 0u, a, b);  // uniform(kp, ()): flat index 0
    float p = fmaxf(0.0f, u01(a ^ b));
    cfg[0] = (p <= 0.6f) ? 1 : 0;
    cfg[1] = (int)km0;
    cfg[2] = (int)km1;
  }
  // randint(kr,(16,8),0,512): span=512 pow2 -> multiplier=0 -> lower_bits % 512,
  // lower_bits = random_bits(k2) where (k1,k2) = split(kr,2) foldlike -> k2 = tf(kr,0,1)
  {
    uint32_t c0, c1, a, b;
    tf2x32(kr10, kr11, 0u, 1u, c0, c1);
    tf2x32(c0, c1, 0u, (uint32_t)t, a, b);
    cfg[3 + t] = (int)((a ^ b) & 511u);
  }
  {
    uint32_t c0, c1, a, b;
    tf2x32(kr20, kr21, 0u, 1u, c0, c1);
    tf2x32(c0, c1, 0u, (uint32_t)t, a, b);
    cfg[131 + t] = (int)((a ^ b) & 511u);
  }
}

// ---------------- C[b,i,j] = sum_l X[b,i,l]*W[j,l] + bias[j] ----------------
__global__ __launch_bounds__(256) void lin_proj(
    const float* __restrict__ X, const float* __restrict__ W,
    const float* __restrict__ bias, float* __restrict__ C) {
  int b = blockIdx.z;
  int j0 = blockIdx.x * 64, i0 = blockIdx.y * 64;
  const float* Xb = X + (size_t)b * (A_ * A_);
  __shared__ float Xs[16][68];  // [l][i], transposed for contiguous ds_read_b128
  __shared__ float Ws[16][68];  // [l][j]
  int tid = threadIdx.x;
  int tx = tid & 15, ty = tid >> 4;
  int lr = tid >> 2, lc = (tid & 3) * 4;  // 64 rows x 16 cols loads
  float acc[4][4] = {{0.f}};
  for (int l0 = 0; l0 < A_; l0 += 16) {
    float4 xv = *(const float4*)(Xb + (i0 + lr) * A_ + l0 + lc);
    float4 wv = *(const float4*)(W + (j0 + lr) * A_ + l0 + lc);
    __syncthreads();
    Xs[lc + 0][lr] = xv.x; Xs[lc + 1][lr] = xv.y; Xs[lc + 2][lr] = xv.z; Xs[lc + 3][lr] = xv.w;
    Ws[lc + 0][lr] = wv.x; Ws[lc + 1][lr] = wv.y; Ws[lc + 2][lr] = wv.z; Ws[lc + 3][lr] = wv.w;
    __syncthreads();
#pragma unroll
    for (int l = 0; l < 16; ++l) {
      float4 a4 = *(const float4*)&Xs[l][ty * 4];
      float4 b4 = *(const float4*)&Ws[l][tx * 4];
      float av[4] = {a4.x, a4.y, a4.z, a4.w};
      float bv[4] = {b4.x, b4.y, b4.z, b4.w};
#pragma unroll
      for (int r = 0; r < 4; ++r)
#pragma unroll
        for (int s = 0; s < 4; ++s) acc[r][s] += av[r] * bv[s];
    }
  }
  float bj[4];
#pragma unroll
  for (int s = 0; s < 4; ++s) bj[s] = bias[j0 + tx * 4 + s];
#pragma unroll
  for (int r = 0; r < 4; ++r) {
    float4 o;
    o.x = acc[r][0] + bj[0]; o.y = acc[r][1] + bj[1];
    o.z = acc[r][2] + bj[2]; o.w = acc[r][3] + bj[3];
    *(float4*)(C + (size_t)b * (A_ * A_) + (i0 + ty * 4 + r) * A_ + j0 + tx * 4) = o;
  }
}

// ---------------- am0[b,i,k] = (sum_j Qp[b,j,i]*Kp[b,j,k]) / sqrt(8) ----------------
__global__ __launch_bounds__(256) void am_kernel(
    const float* __restrict__ Qp, const float* __restrict__ Kp,
    float* __restrict__ am0) {
  int b = blockIdx.z;
  int k0 = blockIdx.x * 64, i0 = blockIdx.y * 64;
  const float* Qb = Qp + (size_t)b * (A_ * A_);
  const float* Kb = Kp + (size_t)b * (A_ * A_);
  __shared__ float Qs[16][68];  // [j][i]
  __shared__ float Ks[16][68];  // [j][k]
  int tid = threadIdx.x;
  int tx = tid & 15, ty = tid >> 4;
  int lr = tid >> 4, lc = (tid & 15) * 4;  // 16 rows(j) x 64 cols loads
  float acc[4][4] = {{0.f}};
  for (int j0 = 0; j0 < A_; j0 += 16) {
    float4 qv = *(const float4*)(Qb + (j0 + lr) * A_ + i0 + lc);
    float4 kv = *(const float4*)(Kb + (j0 + lr) * A_ + k0 + lc);
    __syncthreads();
    *(float4*)&Qs[lr][lc] = qv;
    *(float4*)&Ks[lr][lc] = kv;
    __syncthreads();
#pragma unroll
    for (int j = 0; j < 16; ++j) {
      float4 a4 = *(const float4*)&Qs[j][ty * 4];
      float4 b4 = *(const float4*)&Ks[j][tx * 4];
      float av[4] = {a4.x, a4.y, a4.z, a4.w};
      float bv[4] = {b4.x, b4.y, b4.z, b4.w};
#pragma unroll
      for (int r = 0; r < 4; ++r)
#pragma unroll
        for (int s = 0; s < 4; ++s) acc[r][s] += av[r] * bv[s];
    }
  }
  const float scale = 0.35355339059327373f;  // 1/sqrt(8)
#pragma unroll
  for (int r = 0; r < 4; ++r) {
    float4 o;
    o.x = acc[r][0] * scale; o.y = acc[r][1] * scale;
    o.z = acc[r][2] * scale; o.w = acc[r][3] * scale;
    *(float4*)(am0 + (size_t)b * (A_ * A_) + (i0 + ty * 4 + r) * A_ + k0 + tx * 4) = o;
  }
}

// ---------------- Vp[b,j] = sum_l V[b,l]*WV[j,l] + bias[j] ----------------
__global__ __launch_bounds__(256) void vp_kernel(
    const float* __restrict__ V, const float* __restrict__ W,
    const float* __restrict__ bias, float* __restrict__ Vp) {
  int g = blockIdx.x * 256 + threadIdx.x;
  int b = g >> 9, j = g & 511;
  int t = threadIdx.x;
  __shared__ float vsh[512];
  int bb = (blockIdx.x * 256) >> 9;  // constant within block
  vsh[t] = V[(bb << 9) + t];
  vsh[t + 256] = V[(bb << 9) + t + 256];
  __syncthreads();
  float acc = bias[j];
  const float* wr = W + (size_t)j * A_;
  for (int l = 0; l < A_; ++l) acc += vsh[l] * wr[l];
  Vp[g] = acc;
}

// ---------------- fused mutate/crossover + softmax + PV ----------------
// one block per (b,i); loops heads; out_att[(b*8+h)*512 + i]
__global__ __launch_bounds__(256) void soft_kernel(
    const float* __restrict__ am0, const float* __restrict__ Vp,
    const int* __restrict__ cfg, float* __restrict__ out_att) {
  int bid = blockIdx.x;
  int b = bid >> 9, i = bid & 511;
  int tid = threadIdx.x;
  __shared__ float row[512];
  __shared__ float vsh[512];
  __shared__ float red[8];
  const float* arow = am0 + ((size_t)((b << 9) + i)) * A_;
  row[tid] = arow[tid];
  row[tid + 256] = arow[tid + 256];
  vsh[tid] = Vp[(b << 9) + tid];
  vsh[tid + 256] = Vp[(b << 9) + tid + 256];
  int flag = cfg[0];
  uint32_t km0 = (uint32_t)cfg[1], km1 = (uint32_t)cfg[2];
  __syncthreads();
  int k0 = tid, k1 = tid + 256;
  float v0 = vsh[k0], v1 = vsh[k1];
  float r0 = row[k0], r1v = row[k1];
  for (int h = 0; h < H_; ++h) {
    float x0, x1;
    if (flag) {
      uint32_t base = ((uint32_t)((b * 8 + h) * 512 + i)) * 512u;
      x0 = r0 * mutval(km0, km1, base + (uint32_t)k0);
      x1 = r1v * mutval(km0, km1, base + (uint32_t)k1);
    } else {
      int rr1 = cfg[3 + b * 8 + h];
      int rr2 = cfg[131 + b * 8 + h];
      int src = (i == rr2) ? rr1 : ((i == rr1) ? rr2 : i);
      x0 = r0; x1 = r1v;  // k0 < 256 < 359 never in tail
      if (src != i && k1 >= C_CROSS)
        x1 = am0[((size_t)((b << 9) + src)) * A_ + k1];
    }
    // block max
    float mx = fmaxf(x0, x1);
#pragma unroll
    for (int off = 32; off; off >>= 1) mx = fmaxf(mx, __shfl_xor(mx, off));
    if ((tid & 63) == 0) red[tid >> 6] = mx;
    __syncthreads();
    mx = fmaxf(fmaxf(red[0], red[1]), fmaxf(red[2], red[3]));
    __syncthreads();
    float e0 = __expf(x0 - mx), e1 = __expf(x1 - mx);
    float s = e0 + e1;
    float w = e0 * v0 + e1 * v1;
#pragma unroll
    for (int off = 32; off; off >>= 1) { s += __shfl_xor(s, off); w += __shfl_xor(w, off); }
    if ((tid & 63) == 0) { red[tid >> 6] = s; red[4 + (tid >> 6)] = w; }
    __syncthreads();
    if (tid == 0) {
      float ss = red[0] + red[1] + red[2] + red[3];
      float ww = red[4] + red[5] + red[6] + red[7];
      out_att[((b * 8 + h) << 9) + i] = ww / ss;
    }
    __syncthreads();
  }
}

// ---------------- out[b,j] = sum_t oa[b,t]*WO[j,t] + bias[j] ----------------
__global__ __launch_bounds__(256) void final_kernel(
    const float* __restrict__ oa, const float* __restrict__ WO,
    const float* __restrict__ bias, float* __restrict__ out) {
  int b = blockIdx.y;
  __shared__ float sa[4096];
  int tid = threadIdx.x;
  for (int t = tid; t < 4096; t += 256) sa[t] = oa[b * 4096 + t];
  __syncthreads();
  int wv = tid >> 6, lane = tid & 63;
#pragma unroll
  for (int jj = 0; jj < 4; ++jj) {
    int j = blockIdx.x * 16 + wv * 4 + jj;
    const float* wr = WO + (size_t)j * 4096;
    float acc = 0.f;
    for (int t = lane; t < 4096; t += 64) acc += sa[t] * wr[t];
#pragma unroll
    for (int off = 32; off; off >>= 1) acc += __shfl_xor(acc, off);
    if (lane == 0) out[(b << 9) + j] = acc + bias[j];
  }
}

extern "C" void kernel_launch(void* const* d_in, const int* in_sizes, int n_in,
                              void* d_out, int out_size, void* d_ws, size_t ws_size,
                              hipStream_t stream) {
  (void)in_sizes; (void)n_in; (void)out_size; (void)ws_size;
  const float* Q    = (const float*)d_in[0];
  const float* K    = (const float*)d_in[1];
  const float* V    = (const float*)d_in[2];
  const float* WQ_w = (const float*)d_in[3];
  const float* WQ_b = (const float*)d_in[4];
  const float* WK_w = (const float*)d_in[5];
  const float* WK_b = (const float*)d_in[6];
  const float* WV_w = (const float*)d_in[7];
  const float* WV_b = (const float*)d_in[8];
  const float* WO_w = (const float*)d_in[9];
  const float* WO_b = (const float*)d_in[10];
  float* out = (float*)d_out;

  // workspace: Qp(16MB) Kp(16MB) am0(16MB) Vp(32KB) out_att(256KB) cfg(~1KB)  => ~50.6MB
  char* ws = (char*)d_ws;
  float* Qp  = (float*)(ws);
  float* Kp  = (float*)(ws + (size_t)(1u << 24));
  float* am0 = (float*)(ws + (size_t)(2u << 24));
  float* Vp  = (float*)(ws + (size_t)(3u << 24));
  float* oa  = (float*)(ws + (size_t)(3u << 24) + 65536);
  int*   cfg = (int*)  (ws + (size_t)(3u << 24) + 65536 + 262144);

  lin_proj<<<dim3(8, 8, 16), 256, 0, stream>>>(Q, WQ_w, WQ_b, Qp);
  lin_proj<<<dim3(8, 8, 16), 256, 0, stream>>>(K, WK_w, WK_b, Kp);
  vp_kernel<<<32, 256, 0, stream>>>(V, WV_w, WV_b, Vp);
  rand_kernel<<<1, 128, 0, stream>>>(cfg);
  am_kernel<<<dim3(8, 8, 16), 256, 0, stream>>>(Qp, Kp, am0);
  soft_kernel<<<8192, 256, 0, stream>>>(am0, Vp, cfg, oa);
  final_kernel<<<dim3(32, 16), 256, 0, stream>>>(oa, WO_w, WO_b, out);
}

// Round 3
// 321.369 us; speedup vs baseline: 1.4090x; 1.4090x over previous
//
#include <hip/hip_runtime.h>
#include <stdint.h>
#include <string.h>

// B=16, A=512, H=8, c = 512 - int(512*0.3) = 359
#define B_ 16
#define A_ 512
#define H_ 8
#define C_CROSS 359

typedef short short8 __attribute__((ext_vector_type(8)));
typedef float floatx4 __attribute__((ext_vector_type(4)));

// ---------------- threefry2x32 (exact JAX semantics, host+device) ----------------
__host__ __device__ __forceinline__ void tf2x32(uint32_t k0, uint32_t k1,
                                                uint32_t x0, uint32_t x1,
                                                uint32_t& o0, uint32_t& o1) {
  uint32_t ks2 = k0 ^ k1 ^ 0x1BD11BDAu;
  x0 += k0; x1 += k1;
#define TFR(r) { x0 += x1; x1 = (x1 << (r)) | (x1 >> (32 - (r))); x1 ^= x0; }
  TFR(13) TFR(15) TFR(26) TFR(6)   x0 += k1;  x1 += ks2 + 1u;
  TFR(17) TFR(29) TFR(16) TFR(24)  x0 += ks2; x1 += k0 + 2u;
  TFR(13) TFR(15) TFR(26) TFR(6)   x0 += k0;  x1 += k1 + 3u;
  TFR(17) TFR(29) TFR(16) TFR(24)  x0 += k1;  x1 += ks2 + 4u;
  TFR(13) TFR(15) TFR(26) TFR(6)   x0 += ks2; x1 += k0 + 5u;
#undef TFR
  o0 = x0; o1 = x1;
}

__host__ __device__ __forceinline__ float bits2u01(uint32_t bits) {
  uint32_t v = (bits >> 9) | 0x3f800000u;
  float f;
#ifdef __HIP_DEVICE_COMPILE__
  f = __uint_as_float(v);
#else
  memcpy(&f, &v, 4);
#endif
  return f - 1.0f;
}

// partitionable: random_bits[L] = o0^o1 of tf2x32(k, 0, L)
__device__ __forceinline__ float mutval(uint32_t km0, uint32_t km1, uint32_t L) {
  uint32_t a, b;
  tf2x32(km0, km1, 0u, L, a, b);
  float u = bits2u01(a ^ b);
  return fmaxf(0.7f, u * (1.3f - 0.7f) + 0.7f);
}

// ---------------- bf16 split helpers ----------------
__device__ __forceinline__ uint32_t f2bf(float x) {
  uint32_t u = __float_as_uint(x);
  return (u + 0x7fffu + ((u >> 16) & 1u)) >> 16;  // RNE
}
__device__ __forceinline__ float bf2f(uint32_t h) {
  return __uint_as_float(h << 16);
}

// =====================================================================
// lin_mfma: C[m][d] = sum_l X[m][l]*W[d][l] + bias[d], written TRANSPOSED:
//   O[(b*512 + d)*512 + i]  where m = b*512+i.   z=0: Q-proj, z=1: K-proj.
// split-bf16 (hi+lo) MFMA, fp32-grade accuracy.
// =====================================================================
__global__ __launch_bounds__(256) void lin_mfma(
    const float* __restrict__ Xq, const float* __restrict__ Wq,
    const float* __restrict__ bq, float* __restrict__ Oq,
    const float* __restrict__ Xk, const float* __restrict__ Wk,
    const float* __restrict__ bk, float* __restrict__ Ok) {
  const float *X, *W, *bias; float* O;
  if (blockIdx.z == 0) { X = Xq; W = Wq; bias = bq; O = Oq; }
  else                 { X = Xk; W = Wk; bias = bk; O = Ok; }

  __shared__ __align__(16) char smem[20480];
  ushort (*ah)[40] = (ushort(*)[40])(smem);
  ushort (*al)[40] = (ushort(*)[40])(smem + 5120);
  ushort (*bh)[40] = (ushort(*)[40])(smem + 10240);
  ushort (*bl)[40] = (ushort(*)[40])(smem + 15360);
  float  (*cs)[72] = (float(*)[72])(smem);  // epilogue alias, 18432B

  int tid = threadIdx.x;
  int bm0 = blockIdx.y * 64;   // M rows (b,i) absolute
  int bn0 = blockIdx.x * 64;   // N cols d
  int r = tid >> 2, sg = tid & 3;
  int w = tid >> 6, lane = tid & 63;
  int wm = (w >> 1) * 32, wn = (w & 1) * 32;
  int quad = lane >> 4, l16 = lane & 15;

  floatx4 acc[2][2] = {};
  const float* Arow = X + (size_t)(bm0 + r) * A_ + sg * 8;
  const float* Brow = W + (size_t)(bn0 + r) * A_ + sg * 8;

  for (int k0 = 0; k0 < A_; k0 += 32) {
    float4 a0 = *(const float4*)(Arow + k0);
    float4 a1 = *(const float4*)(Arow + k0 + 4);
    float4 b0 = *(const float4*)(Brow + k0);
    float4 b1 = *(const float4*)(Brow + k0 + 4);
    __syncthreads();
    {
      float xs[8] = {a0.x, a0.y, a0.z, a0.w, a1.x, a1.y, a1.z, a1.w};
      short8 hv, lv;
#pragma unroll
      for (int j = 0; j < 8; ++j) {
        uint32_t hb = f2bf(xs[j]);
        hv[j] = (short)hb;
        lv[j] = (short)f2bf(xs[j] - bf2f(hb));
      }
      *(short8*)&ah[r][sg * 8] = hv;
      *(short8*)&al[r][sg * 8] = lv;
    }
    {
      float xs[8] = {b0.x, b0.y, b0.z, b0.w, b1.x, b1.y, b1.z, b1.w};
      short8 hv, lv;
#pragma unroll
      for (int j = 0; j < 8; ++j) {
        uint32_t hb = f2bf(xs[j]);
        hv[j] = (short)hb;
        lv[j] = (short)f2bf(xs[j] - bf2f(hb));
      }
      *(short8*)&bh[r][sg * 8] = hv;
      *(short8*)&bl[r][sg * 8] = lv;
    }
    __syncthreads();
    short8 afh[2], afl[2], bfh[2], bfl[2];
#pragma unroll
    for (int t2 = 0; t2 < 2; ++t2) {
      afh[t2] = *(const short8*)&ah[wm + t2 * 16 + l16][quad * 8];
      afl[t2] = *(const short8*)&al[wm + t2 * 16 + l16][quad * 8];
      bfh[t2] = *(const short8*)&bh[wn + t2 * 16 + l16][quad * 8];
      bfl[t2] = *(const short8*)&bl[wn + t2 * 16 + l16][quad * 8];
    }
#pragma unroll
    for (int mt = 0; mt < 2; ++mt)
#pragma unroll
      for (int nt = 0; nt < 2; ++nt) {
        acc[mt][nt] = __builtin_amdgcn_mfma_f32_16x16x32_bf16(afh[mt], bfh[nt], acc[mt][nt], 0, 0, 0);
        acc[mt][nt] = __builtin_amdgcn_mfma_f32_16x16x32_bf16(afh[mt], bfl[nt], acc[mt][nt], 0, 0, 0);
        acc[mt][nt] = __builtin_amdgcn_mfma_f32_16x16x32_bf16(afl[mt], bfh[nt], acc[mt][nt], 0, 0, 0);
      }
  }
  __syncthreads();
#pragma unroll
  for (int mt = 0; mt < 2; ++mt)
#pragma unroll
    for (int nt = 0; nt < 2; ++nt)
#pragma unroll
      for (int rr = 0; rr < 4; ++rr)
        cs[wm + mt * 16 + quad * 4 + rr][wn + nt * 16 + l16] = acc[mt][nt][rr];
  __syncthreads();
  int b = bm0 >> 9, i0 = bm0 & 511;
  int dl = tid >> 2, isg = (tid & 3) * 16;
  float bv = bias[bn0 + dl];
  float* op = O + ((size_t)(b * A_ + bn0 + dl)) * A_ + i0 + isg;
  float tmp[16];
#pragma unroll
  for (int ii = 0; ii < 16; ++ii) tmp[ii] = cs[isg + ii][dl] + bv;
#pragma unroll
  for (int ii = 0; ii < 4; ++ii) *(float4*)(op + ii * 4) = *(float4*)&tmp[ii * 4];
}

// =====================================================================
// am_mfma: am0[b][i][k] = (sum_j QpT[b][i][j] * KpT[b][k][j]) / sqrt(8)
// =====================================================================
__global__ __launch_bounds__(256) void am_mfma(
    const float* __restrict__ Qt, const float* __restrict__ Kt,
    float* __restrict__ am0) {
  int bz = blockIdx.z;
  const float* Ap = Qt + (size_t)bz * A_ * A_;
  const float* Bp = Kt + (size_t)bz * A_ * A_;

  __shared__ __align__(16) char smem[20480];
  ushort (*ah)[40] = (ushort(*)[40])(smem);
  ushort (*al)[40] = (ushort(*)[40])(smem + 5120);
  ushort (*bh)[40] = (ushort(*)[40])(smem + 10240);
  ushort (*bl)[40] = (ushort(*)[40])(smem + 15360);

  int tid = threadIdx.x;
  int bm0 = blockIdx.y * 64;   // i
  int bn0 = blockIdx.x * 64;   // k
  int r = tid >> 2, sg = tid & 3;
  int w = tid >> 6, lane = tid & 63;
  int wm = (w >> 1) * 32, wn = (w & 1) * 32;
  int quad = lane >> 4, l16 = lane & 15;

  floatx4 acc[2][2] = {};
  const float* Arow = Ap + (size_t)(bm0 + r) * A_ + sg * 8;
  const float* Brow = Bp + (size_t)(bn0 + r) * A_ + sg * 8;

  for (int k0 = 0; k0 < A_; k0 += 32) {
    float4 a0 = *(const float4*)(Arow + k0);
    float4 a1 = *(const float4*)(Arow + k0 + 4);
    float4 b0 = *(const float4*)(Brow + k0);
    float4 b1 = *(const float4*)(Brow + k0 + 4);
    __syncthreads();
    {
      float xs[8] = {a0.x, a0.y, a0.z, a0.w, a1.x, a1.y, a1.z, a1.w};
      short8 hv, lv;
#pragma unroll
      for (int j = 0; j < 8; ++j) {
        uint32_t hb = f2bf(xs[j]);
        hv[j] = (short)hb;
        lv[j] = (short)f2bf(xs[j] - bf2f(hb));
      }
      *(short8*)&ah[r][sg * 8] = hv;
      *(short8*)&al[r][sg * 8] = lv;
    }
    {
      float xs[8] = {b0.x, b0.y, b0.z, b0.w, b1.x, b1.y, b1.z, b1.w};
      short8 hv, lv;
#pragma unroll
      for (int j = 0; j < 8; ++j) {
        uint32_t hb = f2bf(xs[j]);
        hv[j] = (short)hb;
        lv[j] = (short)f2bf(xs[j] - bf2f(hb));
      }
      *(short8*)&bh[r][sg * 8] = hv;
      *(short8*)&bl[r][sg * 8] = lv;
    }
    __syncthreads();
    short8 afh[2], afl[2], bfh[2], bfl[2];
#pragma unroll
    for (int t2 = 0; t2 < 2; ++t2) {
      afh[t2] = *(const short8*)&ah[wm + t2 * 16 + l16][quad * 8];
      afl[t2] = *(const short8*)&al[wm + t2 * 16 + l16][quad * 8];
      bfh[t2] = *(const short8*)&bh[wn + t2 * 16 + l16][quad * 8];
      bfl[t2] = *(const short8*)&bl[wn + t2 * 16 + l16][quad * 8];
    }
#pragma unroll
    for (int mt = 0; mt < 2; ++mt)
#pragma unroll
      for (int nt = 0; nt < 2; ++nt) {
        acc[mt][nt] = __builtin_amdgcn_mfma_f32_16x16x32_bf16(afh[mt], bfh[nt], acc[mt][nt], 0, 0, 0);
        acc[mt][nt] = __builtin_amdgcn_mfma_f32_16x16x32_bf16(afh[mt], bfl[nt], acc[mt][nt], 0, 0, 0);
        acc[mt][nt] = __builtin_amdgcn_mfma_f32_16x16x32_bf16(afl[mt], bfh[nt], acc[mt][nt], 0, 0, 0);
      }
  }
  const float scale = 0.35355339059327373f;  // 1/sqrt(8)
#pragma unroll
  for (int mt = 0; mt < 2; ++mt)
#pragma unroll
    for (int nt = 0; nt < 2; ++nt)
#pragma unroll
      for (int rr = 0; rr < 4; ++rr) {
        int row = bm0 + wm + mt * 16 + quad * 4 + rr;
        int col = bn0 + wn + nt * 16 + l16;
        am0[((size_t)(bz * A_ + row)) * A_ + col] = acc[mt][nt][rr] * scale;
      }
}

// ---------------- Vp[b,j] = sum_l V[b,l]*WV[j,l] + bias[j] ----------------
__global__ __launch_bounds__(256) void vp_kernel(
    const float* __restrict__ V, const float* __restrict__ W,
    const float* __restrict__ bias, float* __restrict__ Vp) {
  int g = blockIdx.x * 256 + threadIdx.x;
  int j = g & 511;
  int t = threadIdx.x;
  __shared__ float vsh[512];
  int bb = (blockIdx.x * 256) >> 9;
  vsh[t] = V[(bb << 9) + t];
  vsh[t + 256] = V[(bb << 9) + t + 256];
  __syncthreads();
  float acc = bias[j];
  const float* wr = W + (size_t)j * A_;
  for (int l = 0; l < A_; ++l) acc += vsh[l] * wr[l];
  Vp[g] = acc;
}

// ---------------- soft: wave-per-row (b,h,i), mutate variant ----------------
__global__ __launch_bounds__(256) void soft_mut(
    const float* __restrict__ am0, const float* __restrict__ Vp,
    float* __restrict__ oa, uint32_t km0, uint32_t km1) {
  int tid = threadIdx.x;
  int w = tid >> 6, lane = tid & 63;
  int rrow = blockIdx.x * 4 + w;
  int b = rrow >> 12, h = (rrow >> 9) & 7, i = rrow & 511;
  const float* ar = am0 + ((size_t)((b << 9) + i)) * A_;
  const float* vr = Vp + (b << 9);
  uint32_t Lb = ((uint32_t)(((b * 8 + h) << 9) + i)) << 9;
  float x[8], vv[8];
#pragma unroll
  for (int j = 0; j < 8; ++j) {
    int k = lane + 64 * j;
    float a = ar[k];
    vv[j] = vr[k];
    x[j] = a * mutval(km0, km1, Lb + (uint32_t)k);
  }
  float mx = x[0];
#pragma unroll
  for (int j = 1; j < 8; ++j) mx = fmaxf(mx, x[j]);
#pragma unroll
  for (int o = 32; o; o >>= 1) mx = fmaxf(mx, __shfl_xor(mx, o));
  float s = 0.f, wsum = 0.f;
#pragma unroll
  for (int j = 0; j < 8; ++j) {
    float e = __expf(x[j] - mx);
    s += e;
    wsum += e * vv[j];
  }
#pragma unroll
  for (int o = 32; o; o >>= 1) { s += __shfl_xor(s, o); wsum += __shfl_xor(wsum, o); }
  if (lane == 0) oa[(((size_t)(b * 8 + h)) << 9) + i] = wsum / s;
}

// ---------------- soft: crossover variant ----------------
struct CrossCfg { int r1[B_ * H_]; int r2[B_ * H_]; };

__global__ __launch_bounds__(256) void soft_cross(
    const float* __restrict__ am0, const float* __restrict__ Vp,
    float* __restrict__ oa, CrossCfg cfg) {
  int tid = threadIdx.x;
  int w = tid >> 6, lane = tid & 63;
  int rrow = blockIdx.x * 4 + w;
  int b = rrow >> 12, h = (rrow >> 9) & 7, i = rrow & 511;
  int rr1 = cfg.r1[b * 8 + h], rr2 = cfg.r2[b * 8 + h];
  int src = (i == rr2) ? rr1 : ((i == rr1) ? rr2 : i);
  const float* ar = am0 + ((size_t)((b << 9) + i)) * A_;
  const float* ar2 = am0 + ((size_t)((b << 9) + src)) * A_;
  const float* vr = Vp + (b << 9);
  float x[8], vv[8];
#pragma unroll
  for (int j = 0; j < 8; ++j) {
    int k = lane + 64 * j;
    vv[j] = vr[k];
    x[j] = (k >= C_CROSS) ? ar2[k] : ar[k];
  }
  float mx = x[0];
#pragma unroll
  for (int j = 1; j < 8; ++j) mx = fmaxf(mx, x[j]);
#pragma unroll
  for (int o = 32; o; o >>= 1) mx = fmaxf(mx, __shfl_xor(mx, o));
  float s = 0.f, wsum = 0.f;
#pragma unroll
  for (int j = 0; j < 8; ++j) {
    float e = __expf(x[j] - mx);
    s += e;
    wsum += e * vv[j];
  }
#pragma unroll
  for (int o = 32; o; o >>= 1) { s += __shfl_xor(s, o); wsum += __shfl_xor(wsum, o); }
  if (lane == 0) oa[(((size_t)(b * 8 + h)) << 9) + i] = wsum / s;
}

// ---------------- out[b,j] = sum_t oa[b,t]*WO[j,t] + bias[j] ----------------
__global__ __launch_bounds__(256) void final_kernel(
    const float* __restrict__ oa, const float* __restrict__ WO,
    const float* __restrict__ bias, float* __restrict__ out) {
  int b = blockIdx.y;
  __shared__ float sa[4096];
  int tid = threadIdx.x;
  for (int t = tid; t < 4096; t += 256) sa[t] = oa[b * 4096 + t];
  __syncthreads();
  int wv = tid >> 6, lane = tid & 63;
#pragma unroll
  for (int jj = 0; jj < 4; ++jj) {
    int j = blockIdx.x * 16 + wv * 4 + jj;
    const float* wr = WO + (size_t)j * 4096;
    float acc = 0.f;
    for (int t = lane; t < 4096; t += 64) acc += sa[t] * wr[t];
#pragma unroll
    for (int off = 32; off; off >>= 1) acc += __shfl_xor(acc, off);
    if (lane == 0) out[(b << 9) + j] = acc + bias[j];
  }
}

extern "C" void kernel_launch(void* const* d_in, const int* in_sizes, int n_in,
                              void* d_out, int out_size, void* d_ws, size_t ws_size,
                              hipStream_t stream) {
  (void)in_sizes; (void)n_in; (void)out_size; (void)ws_size;
  const float* Q    = (const float*)d_in[0];
  const float* K    = (const float*)d_in[1];
  const float* V    = (const float*)d_in[2];
  const float* WQ_w = (const float*)d_in[3];
  const float* WQ_b = (const float*)d_in[4];
  const float* WK_w = (const float*)d_in[5];
  const float* WK_b = (const float*)d_in[6];
  const float* WV_w = (const float*)d_in[7];
  const float* WV_b = (const float*)d_in[8];
  const float* WO_w = (const float*)d_in[9];
  const float* WO_b = (const float*)d_in[10];
  float* out = (float*)d_out;

  // ws: QpT(16MB) KpT(16MB) am0(16MB) Vp(64KB slot) oa(256KB)  ≈ 50.6MB
  char* ws = (char*)d_ws;
  float* Qpt = (float*)(ws);
  float* Kpt = (float*)(ws + (size_t)16777216);
  float* am0 = (float*)(ws + (size_t)2 * 16777216);
  float* Vp  = (float*)(ws + (size_t)3 * 16777216);
  float* oa  = (float*)(ws + (size_t)3 * 16777216 + 65536);

  // ---- host-side deterministic RNG config (partitionable threefry) ----
  uint32_t kp0, kp1, km0, km1, kr10, kr11, kr20, kr21, a, bbits;
  tf2x32(0u, 42u, 0u, 0u, kp0, kp1);
  tf2x32(0u, 42u, 0u, 1u, km0, km1);
  tf2x32(0u, 42u, 0u, 2u, kr10, kr11);
  tf2x32(0u, 42u, 0u, 3u, kr20, kr21);
  tf2x32(kp0, kp1, 0u, 0u, a, bbits);
  float p = bits2u01(a ^ bbits);
  if (p < 0.f) p = 0.f;
  bool mutate = (p <= 0.6f);

  lin_mfma<<<dim3(8, 128, 2), 256, 0, stream>>>(Q, WQ_w, WQ_b, Qpt, K, WK_w, WK_b, Kpt);
  vp_kernel<<<32, 256, 0, stream>>>(V, WV_w, WV_b, Vp);
  am_mfma<<<dim3(8, 8, 16), 256, 0, stream>>>(Qpt, Kpt, am0);
  if (mutate) {
    soft_mut<<<16384, 256, 0, stream>>>(am0, Vp, oa, km0, km1);
  } else {
    CrossCfg cfg;
    uint32_t c0, c1;
    tf2x32(kr10, kr11, 0u, 1u, c0, c1);
    for (int t = 0; t < B_ * H_; ++t) {
      tf2x32(c0, c1, 0u, (uint32_t)t, a, bbits);
      cfg.r1[t] = (int)((a ^ bbits) & 511u);
    }
    tf2x32(kr20, kr21, 0u, 1u, c0, c1);
    for (int t = 0; t < B_ * H_; ++t) {
      tf2x32(c0, c1, 0u, (uint32_t)t, a, bbits);
      cfg.r2[t] = (int)((a ^ bbits) & 511u);
    }
    soft_cross<<<16384, 256, 0, stream>>>(am0, Vp, oa, cfg);
  }
  final_kernel<<<dim3(32, 16), 256, 0, stream>>>(oa, WO_w, WO_b, out);
}

// Round 4
// 258.140 us; speedup vs baseline: 1.7541x; 1.2449x over previous
//
#include <hip/hip_runtime.h>
#include <stdint.h>
#include <string.h>

// B=16, A=512, H=8, c = 512 - int(512*0.3) = 359
#define B_ 16
#define A_ 512
#define H_ 8
#define C_CROSS 359

typedef short short8 __attribute__((ext_vector_type(8)));
typedef float floatx4 __attribute__((ext_vector_type(4)));

// ---------------- threefry2x32 (exact JAX semantics, host+device) ----------------
__host__ __device__ __forceinline__ void tf2x32(uint32_t k0, uint32_t k1,
                                                uint32_t x0, uint32_t x1,
                                                uint32_t& o0, uint32_t& o1) {
  uint32_t ks2 = k0 ^ k1 ^ 0x1BD11BDAu;
  x0 += k0; x1 += k1;
#define TFR(r) { x0 += x1; x1 = (x1 << (r)) | (x1 >> (32 - (r))); x1 ^= x0; }
  TFR(13) TFR(15) TFR(26) TFR(6)   x0 += k1;  x1 += ks2 + 1u;
  TFR(17) TFR(29) TFR(16) TFR(24)  x0 += ks2; x1 += k0 + 2u;
  TFR(13) TFR(15) TFR(26) TFR(6)   x0 += k0;  x1 += k1 + 3u;
  TFR(17) TFR(29) TFR(16) TFR(24)  x0 += k1;  x1 += ks2 + 4u;
  TFR(13) TFR(15) TFR(26) TFR(6)   x0 += ks2; x1 += k0 + 5u;
#undef TFR
  o0 = x0; o1 = x1;
}

__host__ __device__ __forceinline__ float bits2u01(uint32_t bits) {
  uint32_t v = (bits >> 9) | 0x3f800000u;
  float f;
#ifdef __HIP_DEVICE_COMPILE__
  f = __uint_as_float(v);
#else
  memcpy(&f, &v, 4);
#endif
  return f - 1.0f;
}

// partitionable: random_bits[L] = o0^o1 of tf2x32(k, 0, L)
__device__ __forceinline__ float mutval(uint32_t km0, uint32_t km1, uint32_t L) {
  uint32_t a, b;
  tf2x32(km0, km1, 0u, L, a, b);
  float u = bits2u01(a ^ b);
  return fmaxf(0.7f, u * (1.3f - 0.7f) + 0.7f);
}

// ---------------- bf16 split helpers ----------------
__device__ __forceinline__ uint32_t f2bf(float x) {
  uint32_t u = __float_as_uint(x);
  return (u + 0x7fffu + ((u >> 16) & 1u)) >> 16;  // RNE
}
__device__ __forceinline__ float bf2f(uint32_t h) {
  return __uint_as_float(h << 16);
}

// =====================================================================
// lin_mfma: C[m][d] = sum_l X[m][l]*W[d][l] + bias[d], written TRANSPOSED:
//   O[(b*512 + d)*512 + i]  where m = b*512+i.   z=0: Q-proj, z=1: K-proj.
// split-bf16 (hi+lo) MFMA, fp32-grade accuracy.
// =====================================================================
__global__ __launch_bounds__(256) void lin_mfma(
    const float* __restrict__ Xq, const float* __restrict__ Wq,
    const float* __restrict__ bq, float* __restrict__ Oq,
    const float* __restrict__ Xk, const float* __restrict__ Wk,
    const float* __restrict__ bk, float* __restrict__ Ok) {
  const float *X, *W, *bias; float* O;
  if (blockIdx.z == 0) { X = Xq; W = Wq; bias = bq; O = Oq; }
  else                 { X = Xk; W = Wk; bias = bk; O = Ok; }

  __shared__ __align__(16) char smem[20480];
  ushort (*ah)[40] = (ushort(*)[40])(smem);
  ushort (*al)[40] = (ushort(*)[40])(smem + 5120);
  ushort (*bh)[40] = (ushort(*)[40])(smem + 10240);
  ushort (*bl)[40] = (ushort(*)[40])(smem + 15360);
  float  (*cs)[72] = (float(*)[72])(smem);  // epilogue alias, 18432B

  int tid = threadIdx.x;
  int bm0 = blockIdx.y * 64;   // M rows (b,i) absolute
  int bn0 = blockIdx.x * 64;   // N cols d
  int r = tid >> 2, sg = tid & 3;
  int w = tid >> 6, lane = tid & 63;
  int wm = (w >> 1) * 32, wn = (w & 1) * 32;
  int quad = lane >> 4, l16 = lane & 15;

  floatx4 acc[2][2] = {};
  const float* Arow = X + (size_t)(bm0 + r) * A_ + sg * 8;
  const float* Brow = W + (size_t)(bn0 + r) * A_ + sg * 8;

  for (int k0 = 0; k0 < A_; k0 += 32) {
    float4 a0 = *(const float4*)(Arow + k0);
    float4 a1 = *(const float4*)(Arow + k0 + 4);
    float4 b0 = *(const float4*)(Brow + k0);
    float4 b1 = *(const float4*)(Brow + k0 + 4);
    __syncthreads();
    {
      float xs[8] = {a0.x, a0.y, a0.z, a0.w, a1.x, a1.y, a1.z, a1.w};
      short8 hv, lv;
#pragma unroll
      for (int j = 0; j < 8; ++j) {
        uint32_t hb = f2bf(xs[j]);
        hv[j] = (short)hb;
        lv[j] = (short)f2bf(xs[j] - bf2f(hb));
      }
      *(short8*)&ah[r][sg * 8] = hv;
      *(short8*)&al[r][sg * 8] = lv;
    }
    {
      float xs[8] = {b0.x, b0.y, b0.z, b0.w, b1.x, b1.y, b1.z, b1.w};
      short8 hv, lv;
#pragma unroll
      for (int j = 0; j < 8; ++j) {
        uint32_t hb = f2bf(xs[j]);
        hv[j] = (short)hb;
        lv[j] = (short)f2bf(xs[j] - bf2f(hb));
      }
      *(short8*)&bh[r][sg * 8] = hv;
      *(short8*)&bl[r][sg * 8] = lv;
    }
    __syncthreads();
    short8 afh[2], afl[2], bfh[2], bfl[2];
#pragma unroll
    for (int t2 = 0; t2 < 2; ++t2) {
      afh[t2] = *(const short8*)&ah[wm + t2 * 16 + l16][quad * 8];
      afl[t2] = *(const short8*)&al[wm + t2 * 16 + l16][quad * 8];
      bfh[t2] = *(const short8*)&bh[wn + t2 * 16 + l16][quad * 8];
      bfl[t2] = *(const short8*)&bl[wn + t2 * 16 + l16][quad * 8];
    }
#pragma unroll
    for (int mt = 0; mt < 2; ++mt)
#pragma unroll
      for (int nt = 0; nt < 2; ++nt) {
        acc[mt][nt] = __builtin_amdgcn_mfma_f32_16x16x32_bf16(afh[mt], bfh[nt], acc[mt][nt], 0, 0, 0);
        acc[mt][nt] = __builtin_amdgcn_mfma_f32_16x16x32_bf16(afh[mt], bfl[nt], acc[mt][nt], 0, 0, 0);
        acc[mt][nt] = __builtin_amdgcn_mfma_f32_16x16x32_bf16(afl[mt], bfh[nt], acc[mt][nt], 0, 0, 0);
      }
  }
  __syncthreads();
#pragma unroll
  for (int mt = 0; mt < 2; ++mt)
#pragma unroll
    for (int nt = 0; nt < 2; ++nt)
#pragma unroll
      for (int rr = 0; rr < 4; ++rr)
        cs[wm + mt * 16 + quad * 4 + rr][wn + nt * 16 + l16] = acc[mt][nt][rr];
  __syncthreads();
  int b = bm0 >> 9, i0 = bm0 & 511;
  int dl = tid >> 2, isg = (tid & 3) * 16;
  float bv = bias[bn0 + dl];
  float* op = O + ((size_t)(b * A_ + bn0 + dl)) * A_ + i0 + isg;
  float tmp[16];
#pragma unroll
  for (int ii = 0; ii < 16; ++ii) tmp[ii] = cs[isg + ii][dl] + bv;
#pragma unroll
  for (int ii = 0; ii < 4; ++ii) *(float4*)(op + ii * 4) = *(float4*)&tmp[ii * 4];
}

// =====================================================================
// am_mfma: am0[b][i][k] = (sum_j QpT[b][i][j] * KpT[b][k][j]) / sqrt(8)
// =====================================================================
__global__ __launch_bounds__(256) void am_mfma(
    const float* __restrict__ Qt, const float* __restrict__ Kt,
    float* __restrict__ am0) {
  int bz = blockIdx.z;
  const float* Ap = Qt + (size_t)bz * A_ * A_;
  const float* Bp = Kt + (size_t)bz * A_ * A_;

  __shared__ __align__(16) char smem[20480];
  ushort (*ah)[40] = (ushort(*)[40])(smem);
  ushort (*al)[40] = (ushort(*)[40])(smem + 5120);
  ushort (*bh)[40] = (ushort(*)[40])(smem + 10240);
  ushort (*bl)[40] = (ushort(*)[40])(smem + 15360);

  int tid = threadIdx.x;
  int bm0 = blockIdx.y * 64;   // i
  int bn0 = blockIdx.x * 64;   // k
  int r = tid >> 2, sg = tid & 3;
  int w = tid >> 6, lane = tid & 63;
  int wm = (w >> 1) * 32, wn = (w & 1) * 32;
  int quad = lane >> 4, l16 = lane & 15;

  floatx4 acc[2][2] = {};
  const float* Arow = Ap + (size_t)(bm0 + r) * A_ + sg * 8;
  const float* Brow = Bp + (size_t)(bn0 + r) * A_ + sg * 8;

  for (int k0 = 0; k0 < A_; k0 += 32) {
    float4 a0 = *(const float4*)(Arow + k0);
    float4 a1 = *(const float4*)(Arow + k0 + 4);
    float4 b0 = *(const float4*)(Brow + k0);
    float4 b1 = *(const float4*)(Brow + k0 + 4);
    __syncthreads();
    {
      float xs[8] = {a0.x, a0.y, a0.z, a0.w, a1.x, a1.y, a1.z, a1.w};
      short8 hv, lv;
#pragma unroll
      for (int j = 0; j < 8; ++j) {
        uint32_t hb = f2bf(xs[j]);
        hv[j] = (short)hb;
        lv[j] = (short)f2bf(xs[j] - bf2f(hb));
      }
      *(short8*)&ah[r][sg * 8] = hv;
      *(short8*)&al[r][sg * 8] = lv;
    }
    {
      float xs[8] = {b0.x, b0.y, b0.z, b0.w, b1.x, b1.y, b1.z, b1.w};
      short8 hv, lv;
#pragma unroll
      for (int j = 0; j < 8; ++j) {
        uint32_t hb = f2bf(xs[j]);
        hv[j] = (short)hb;
        lv[j] = (short)f2bf(xs[j] - bf2f(hb));
      }
      *(short8*)&bh[r][sg * 8] = hv;
      *(short8*)&bl[r][sg * 8] = lv;
    }
    __syncthreads();
    short8 afh[2], afl[2], bfh[2], bfl[2];
#pragma unroll
    for (int t2 = 0; t2 < 2; ++t2) {
      afh[t2] = *(const short8*)&ah[wm + t2 * 16 + l16][quad * 8];
      afl[t2] = *(const short8*)&al[wm + t2 * 16 + l16][quad * 8];
      bfh[t2] = *(const short8*)&bh[wn + t2 * 16 + l16][quad * 8];
      bfl[t2] = *(const short8*)&bl[wn + t2 * 16 + l16][quad * 8];
    }
#pragma unroll
    for (int mt = 0; mt < 2; ++mt)
#pragma unroll
      for (int nt = 0; nt < 2; ++nt) {
        acc[mt][nt] = __builtin_amdgcn_mfma_f32_16x16x32_bf16(afh[mt], bfh[nt], acc[mt][nt], 0, 0, 0);
        acc[mt][nt] = __builtin_amdgcn_mfma_f32_16x16x32_bf16(afh[mt], bfl[nt], acc[mt][nt], 0, 0, 0);
        acc[mt][nt] = __builtin_amdgcn_mfma_f32_16x16x32_bf16(afl[mt], bfh[nt], acc[mt][nt], 0, 0, 0);
      }
  }
  const float scale = 0.35355339059327373f;  // 1/sqrt(8)
#pragma unroll
  for (int mt = 0; mt < 2; ++mt)
#pragma unroll
    for (int nt = 0; nt < 2; ++nt)
#pragma unroll
      for (int rr = 0; rr < 4; ++rr) {
        int row = bm0 + wm + mt * 16 + quad * 4 + rr;
        int col = bn0 + wn + nt * 16 + l16;
        am0[((size_t)(bz * A_ + row)) * A_ + col] = acc[mt][nt][rr] * scale;
      }
}

// =====================================================================
// small_gemm: out[b][j0+j] += sum_{k in chunk} X[b][k] * W[j0+j][k]  (+bias at y==0)
//   X: [16][K] row-major, W: [N][K] row-major, out: [16][512].
//   grid (N/16, K/256). out MUST be pre-zeroed (atomicAdd accumulation).
// =====================================================================
__global__ __launch_bounds__(256) void small_gemm(
    const float* __restrict__ X, const float* __restrict__ W,
    const float* __restrict__ bias, float* __restrict__ out, int K) {
  __shared__ float xs[16 * 260];
  __shared__ float ws[16 * 260];
  int tid = threadIdx.x;
  int j0 = blockIdx.x * 16;
  int k0 = blockIdx.y * 256;
#pragma unroll
  for (int it = 0; it < 4; ++it) {
    int idx = it * 256 + tid;          // [0,1024) float4 units
    int rr = idx >> 6, kk4 = idx & 63; // row, k-quad
    float4 xv = *(const float4*)(X + (size_t)rr * K + k0 + kk4 * 4);
    float4 wv = *(const float4*)(W + (size_t)(j0 + rr) * K + k0 + kk4 * 4);
    *(float4*)&xs[rr * 260 + kk4 * 4] = xv;
    *(float4*)&ws[rr * 260 + kk4 * 4] = wv;
  }
  __syncthreads();
  int b = tid & 15, j = tid >> 4;
  const float* xr = &xs[b * 260];
  const float* wr = &ws[j * 260];
  float acc = 0.f;
#pragma unroll
  for (int kk = 0; kk < 256; kk += 4) {
    float4 a = *(const float4*)(xr + kk);
    float4 w4 = *(const float4*)(wr + kk);
    acc += a.x * w4.x + a.y * w4.y + a.z * w4.z + a.w * w4.w;
  }
  if (blockIdx.y == 0) acc += bias[j0 + j];
  atomicAdd(&out[b * 512 + j0 + j], acc);
}

// ---------------- soft: wave-per-row (b,h,i), mutate variant ----------------
__global__ __launch_bounds__(256) void soft_mut(
    const float* __restrict__ am0, const float* __restrict__ Vp,
    float* __restrict__ oa, uint32_t km0, uint32_t km1) {
  int tid = threadIdx.x;
  int w = tid >> 6, lane = tid & 63;
  int rrow = blockIdx.x * 4 + w;
  int b = rrow >> 12, h = (rrow >> 9) & 7, i = rrow & 511;
  const float* ar = am0 + ((size_t)((b << 9) + i)) * A_;
  const float* vr = Vp + (b << 9);
  uint32_t Lb = ((uint32_t)(((b * 8 + h) << 9) + i)) << 9;
  float x[8], vv[8];
#pragma unroll
  for (int j = 0; j < 8; ++j) {
    int k = lane + 64 * j;
    float a = ar[k];
    vv[j] = vr[k];
    x[j] = a * mutval(km0, km1, Lb + (uint32_t)k);
  }
  float mx = x[0];
#pragma unroll
  for (int j = 1; j < 8; ++j) mx = fmaxf(mx, x[j]);
#pragma unroll
  for (int o = 32; o; o >>= 1) mx = fmaxf(mx, __shfl_xor(mx, o));
  float s = 0.f, wsum = 0.f;
#pragma unroll
  for (int j = 0; j < 8; ++j) {
    float e = __expf(x[j] - mx);
    s += e;
    wsum += e * vv[j];
  }
#pragma unroll
  for (int o = 32; o; o >>= 1) { s += __shfl_xor(s, o); wsum += __shfl_xor(wsum, o); }
  if (lane == 0) oa[(((size_t)(b * 8 + h)) << 9) + i] = wsum / s;
}

// ---------------- soft: crossover variant ----------------
struct CrossCfg { int r1[B_ * H_]; int r2[B_ * H_]; };

__global__ __launch_bounds__(256) void soft_cross(
    const float* __restrict__ am0, const float* __restrict__ Vp,
    float* __restrict__ oa, CrossCfg cfg) {
  int tid = threadIdx.x;
  int w = tid >> 6, lane = tid & 63;
  int rrow = blockIdx.x * 4 + w;
  int b = rrow >> 12, h = (rrow >> 9) & 7, i = rrow & 511;
  int rr1 = cfg.r1[b * 8 + h], rr2 = cfg.r2[b * 8 + h];
  int src = (i == rr2) ? rr1 : ((i == rr1) ? rr2 : i);
  const float* ar = am0 + ((size_t)((b << 9) + i)) * A_;
  const float* ar2 = am0 + ((size_t)((b << 9) + src)) * A_;
  const float* vr = Vp + (b << 9);
  float x[8], vv[8];
#pragma unroll
  for (int j = 0; j < 8; ++j) {
    int k = lane + 64 * j;
    vv[j] = vr[k];
    x[j] = (k >= C_CROSS) ? ar2[k] : ar[k];
  }
  float mx = x[0];
#pragma unroll
  for (int j = 1; j < 8; ++j) mx = fmaxf(mx, x[j]);
#pragma unroll
  for (int o = 32; o; o >>= 1) mx = fmaxf(mx, __shfl_xor(mx, o));
  float s = 0.f, wsum = 0.f;
#pragma unroll
  for (int j = 0; j < 8; ++j) {
    float e = __expf(x[j] - mx);
    s += e;
    wsum += e * vv[j];
  }
#pragma unroll
  for (int o = 32; o; o >>= 1) { s += __shfl_xor(s, o); wsum += __shfl_xor(wsum, o); }
  if (lane == 0) oa[(((size_t)(b * 8 + h)) << 9) + i] = wsum / s;
}

extern "C" void kernel_launch(void* const* d_in, const int* in_sizes, int n_in,
                              void* d_out, int out_size, void* d_ws, size_t ws_size,
                              hipStream_t stream) {
  (void)in_sizes; (void)n_in; (void)out_size; (void)ws_size;
  const float* Q    = (const float*)d_in[0];
  const float* K    = (const float*)d_in[1];
  const float* V    = (const float*)d_in[2];
  const float* WQ_w = (const float*)d_in[3];
  const float* WQ_b = (const float*)d_in[4];
  const float* WK_w = (const float*)d_in[5];
  const float* WK_b = (const float*)d_in[6];
  const float* WV_w = (const float*)d_in[7];
  const float* WV_b = (const float*)d_in[8];
  const float* WO_w = (const float*)d_in[9];
  const float* WO_b = (const float*)d_in[10];
  float* out = (float*)d_out;

  // ws: QpT(16MB) KpT(16MB) am0(16MB) Vp(64KB slot) oa(256KB)  ≈ 50.6MB
  char* ws = (char*)d_ws;
  float* Qpt = (float*)(ws);
  float* Kpt = (float*)(ws + (size_t)16777216);
  float* am0 = (float*)(ws + (size_t)2 * 16777216);
  float* Vp  = (float*)(ws + (size_t)3 * 16777216);
  float* oa  = (float*)(ws + (size_t)3 * 16777216 + 65536);

  // ---- host-side deterministic RNG config (partitionable threefry) ----
  uint32_t kp0, kp1, km0, km1, kr10, kr11, kr20, kr21, a, bbits;
  tf2x32(0u, 42u, 0u, 0u, kp0, kp1);
  tf2x32(0u, 42u, 0u, 1u, km0, km1);
  tf2x32(0u, 42u, 0u, 2u, kr10, kr11);
  tf2x32(0u, 42u, 0u, 3u, kr20, kr21);
  tf2x32(kp0, kp1, 0u, 0u, a, bbits);
  float p = bits2u01(a ^ bbits);
  if (p < 0.f) p = 0.f;
  bool mutate = (p <= 0.6f);

  // zero atomicAdd targets (graph-capture-safe async memsets)
  hipMemsetAsync(Vp, 0, 16 * 512 * sizeof(float), stream);
  hipMemsetAsync(out, 0, 16 * 512 * sizeof(float), stream);

  lin_mfma<<<dim3(8, 128, 2), 256, 0, stream>>>(Q, WQ_w, WQ_b, Qpt, K, WK_w, WK_b, Kpt);
  small_gemm<<<dim3(32, 2), 256, 0, stream>>>(V, WV_w, WV_b, Vp, 512);
  am_mfma<<<dim3(8, 8, 16), 256, 0, stream>>>(Qpt, Kpt, am0);
  if (mutate) {
    soft_mut<<<16384, 256, 0, stream>>>(am0, Vp, oa, km0, km1);
  } else {
    CrossCfg cfg;
    uint32_t c0, c1;
    tf2x32(kr10, kr11, 0u, 1u, c0, c1);
    for (int t = 0; t < B_ * H_; ++t) {
      tf2x32(c0, c1, 0u, (uint32_t)t, a, bbits);
      cfg.r1[t] = (int)((a ^ bbits) & 511u);
    }
    tf2x32(kr20, kr21, 0u, 1u, c0, c1);
    for (int t = 0; t < B_ * H_; ++t) {
      tf2x32(c0, c1, 0u, (uint32_t)t, a, bbits);
      cfg.r2[t] = (int)((a ^ bbits) & 511u);
    }
    soft_cross<<<16384, 256, 0, stream>>>(am0, Vp, oa, cfg);
  }
  small_gemm<<<dim3(32, 16), 256, 0, stream>>>(oa, WO_w, WO_b, out, 4096);
}

// Round 5
// 250.741 us; speedup vs baseline: 1.8059x; 1.0295x over previous
//
#include <hip/hip_runtime.h>
#include <stdint.h>
#include <string.h>

// B=16, A=512, H=8, c = 512 - int(512*0.3) = 359
#define B_ 16
#define A_ 512
#define H_ 8
#define C_CROSS 359
#define LDSTRIDE 40  // ushorts per 32-k LDS row (80 B, 16B-aligned, odd in 16B units)

typedef short short8 __attribute__((ext_vector_type(8)));
typedef float floatx4 __attribute__((ext_vector_type(4)));

// ---------------- threefry2x32 (exact JAX semantics, host+device) ----------------
__host__ __device__ __forceinline__ uint32_t rotl32(uint32_t x, int r) {
#ifdef __HIP_DEVICE_COMPILE__
  return __builtin_amdgcn_alignbit(x, x, 32 - r);  // v_alignbit_b32: 1 instr rotate
#else
  return (x << r) | (x >> (32 - r));
#endif
}

__host__ __device__ __forceinline__ void tf2x32(uint32_t k0, uint32_t k1,
                                                uint32_t x0, uint32_t x1,
                                                uint32_t& o0, uint32_t& o1) {
  uint32_t ks2 = k0 ^ k1 ^ 0x1BD11BDAu;
  x0 += k0; x1 += k1;
#define TFR(r) { x0 += x1; x1 = rotl32(x1, r); x1 ^= x0; }
  TFR(13) TFR(15) TFR(26) TFR(6)   x0 += k1;  x1 += ks2 + 1u;
  TFR(17) TFR(29) TFR(16) TFR(24)  x0 += ks2; x1 += k0 + 2u;
  TFR(13) TFR(15) TFR(26) TFR(6)   x0 += k0;  x1 += k1 + 3u;
  TFR(17) TFR(29) TFR(16) TFR(24)  x0 += k1;  x1 += ks2 + 4u;
  TFR(13) TFR(15) TFR(26) TFR(6)   x0 += ks2; x1 += k0 + 5u;
#undef TFR
  o0 = x0; o1 = x1;
}

__host__ __device__ __forceinline__ float bits2u01(uint32_t bits) {
  uint32_t v = (bits >> 9) | 0x3f800000u;
  float f;
#ifdef __HIP_DEVICE_COMPILE__
  f = __uint_as_float(v);
#else
  memcpy(&f, &v, 4);
#endif
  return f - 1.0f;
}

// partitionable: random_bits[L] = o0^o1 of tf2x32(k, 0, L)
__device__ __forceinline__ float mutval(uint32_t km0, uint32_t km1, uint32_t L) {
  uint32_t a, b;
  tf2x32(km0, km1, 0u, L, a, b);
  float u = bits2u01(a ^ b);
  return fmaxf(0.7f, u * (1.3f - 0.7f) + 0.7f);
}

// ---------------- bf16 split helpers ----------------
__device__ __forceinline__ uint32_t f2bf(float x) {
  uint32_t u = __float_as_uint(x);
  return (u + 0x7fffu + ((u >> 16) & 1u)) >> 16;  // RNE
}
__device__ __forceinline__ float bf2f(uint32_t h) {
  return __uint_as_float(h << 16);
}

__device__ __forceinline__ void split8(const float* p, short8& h, short8& l) {
  float4 v0 = *(const float4*)p;
  float4 v1 = *(const float4*)(p + 4);
  float xs[8] = {v0.x, v0.y, v0.z, v0.w, v1.x, v1.y, v1.z, v1.w};
#pragma unroll
  for (int j = 0; j < 8; ++j) {
    uint32_t hb = f2bf(xs[j]);
    h[j] = (short)hb;
    l[j] = (short)f2bf(xs[j] - bf2f(hb));
  }
}

// =====================================================================
// lin_mfma2: 128x128 tile. C[m][d] = sum_l X[m][l]*W[d][l] + bias[d].
// Output written TRANSPOSED and PRE-SPLIT to bf16 hi/lo:
//   OH/OL[(b*512 + d)*512 + i],  m = b*512 + i.
// grid: 512 blocks 1-D: z = bid>>8 (0=Q,1=K), ti = (bid&255)>>2, tn = bid&3.
// =====================================================================
__global__ __launch_bounds__(256, 2) void lin_mfma2(
    const float* __restrict__ Xq, const float* __restrict__ Wq,
    const float* __restrict__ bq, ushort* __restrict__ QptH, ushort* __restrict__ QptL,
    const float* __restrict__ Xk, const float* __restrict__ Wk,
    const float* __restrict__ bk, ushort* __restrict__ KptH, ushort* __restrict__ KptL) {
  int bid = blockIdx.x;
  int z = bid >> 8;
  int rem = bid & 255;
  int ti = rem >> 2, tn = rem & 3;
  const float* X = z ? Xk : Xq;
  const float* W = z ? Wk : Wq;
  const float* bias = z ? bk : bq;
  ushort* OH = z ? KptH : QptH;
  ushort* OL = z ? KptL : QptL;

  __shared__ __align__(16) char smem[40960];
  ushort (*Ah)[LDSTRIDE] = (ushort(*)[LDSTRIDE])(smem);
  ushort (*Al)[LDSTRIDE] = (ushort(*)[LDSTRIDE])(smem + 10240);
  ushort (*Bh)[LDSTRIDE] = (ushort(*)[LDSTRIDE])(smem + 20480);
  ushort (*Bl)[LDSTRIDE] = (ushort(*)[LDSTRIDE])(smem + 30720);
  uint32_t (*cs)[132] = (uint32_t(*)[132])(smem);  // epilogue alias: 64*132*4 = 33792 B

  int tid = threadIdx.x;
  int w = tid >> 6, lane = tid & 63, quad = lane >> 4, l16 = lane & 15;
  int wm = (w >> 1) * 64, wn = (w & 1) * 64;
  int m0 = ti * 128;  // global row (b*512+i)
  int n0 = tn * 128;  // d

  float bv[4];
#pragma unroll
  for (int nt = 0; nt < 4; ++nt) bv[nt] = bias[n0 + wn + nt * 16 + l16];

  floatx4 acc[4][4] = {};

  for (int k0 = 0; k0 < 512; k0 += 32) {
    short8 ha[2], la[2], hb[2], lb[2];
#pragma unroll
    for (int g = 0; g < 2; ++g) {
      int gid = g * 256 + tid;
      int m = gid >> 2, kg = gid & 3;
      split8(X + (size_t)(m0 + m) * 512 + k0 + kg * 8, ha[g], la[g]);
      split8(W + (size_t)(n0 + m) * 512 + k0 + kg * 8, hb[g], lb[g]);
    }
    __syncthreads();
#pragma unroll
    for (int g = 0; g < 2; ++g) {
      int gid = g * 256 + tid;
      int m = gid >> 2, kg = gid & 3;
      *(short8*)&Ah[m][kg * 8] = ha[g];
      *(short8*)&Al[m][kg * 8] = la[g];
      *(short8*)&Bh[m][kg * 8] = hb[g];
      *(short8*)&Bl[m][kg * 8] = lb[g];
    }
    __syncthreads();
    short8 fAh[4], fAl[4], fBh[4], fBl[4];
#pragma unroll
    for (int t4 = 0; t4 < 4; ++t4) {
      int ma = wm + t4 * 16 + l16;
      int nb = wn + t4 * 16 + l16;
      fAh[t4] = *(const short8*)&Ah[ma][quad * 8];
      fAl[t4] = *(const short8*)&Al[ma][quad * 8];
      fBh[t4] = *(const short8*)&Bh[nb][quad * 8];
      fBl[t4] = *(const short8*)&Bl[nb][quad * 8];
    }
#pragma unroll
    for (int mt = 0; mt < 4; ++mt)
#pragma unroll
      for (int nt = 0; nt < 4; ++nt) {
        acc[mt][nt] = __builtin_amdgcn_mfma_f32_16x16x32_bf16(fAh[mt], fBh[nt], acc[mt][nt], 0, 0, 0);
        acc[mt][nt] = __builtin_amdgcn_mfma_f32_16x16x32_bf16(fAh[mt], fBl[nt], acc[mt][nt], 0, 0, 0);
        acc[mt][nt] = __builtin_amdgcn_mfma_f32_16x16x32_bf16(fAl[mt], fBh[nt], acc[mt][nt], 0, 0, 0);
      }
  }

  // epilogue: +bias, split to hi/lo, transpose via LDS (two 64-col passes)
  __syncthreads();
  int bb = m0 >> 9, i0 = m0 & 511;
  for (int p = 0; p < 2; ++p) {
    if ((w & 1) == p) {
#pragma unroll
      for (int mt = 0; mt < 4; ++mt)
#pragma unroll
        for (int nt = 0; nt < 4; ++nt)
#pragma unroll
          for (int rr = 0; rr < 4; ++rr) {
            float val = acc[mt][nt][rr] + bv[nt];
            uint32_t hb2 = f2bf(val);
            uint32_t lb2 = f2bf(val - bf2f(hb2));
            cs[nt * 16 + l16][wm + mt * 16 + quad * 4 + rr] = (hb2 << 16) | lb2;
          }
    }
    __syncthreads();
    {
      int col_l = tid >> 2, iseg = (tid & 3) * 32;
      int d = n0 + p * 64 + col_l;
      size_t obase = ((size_t)(bb * 512 + d)) * 512 + i0 + iseg;
      ushort* oh = OH + obase;
      ushort* ol = OL + obase;
#pragma unroll
      for (int sgi = 0; sgi < 4; ++sgi) {
        short8 hv, lv;
#pragma unroll
        for (int j = 0; j < 8; ++j) {
          uint32_t v = cs[col_l][iseg + sgi * 8 + j];
          hv[j] = (short)(v >> 16);
          lv[j] = (short)(v & 0xffffu);
        }
        *(short8*)(oh + sgi * 8) = hv;
        *(short8*)(ol + sgi * 8) = lv;
      }
    }
    __syncthreads();
  }
}

// =====================================================================
// am_mfma2: am0[b][i][k] = (sum_j Qpt[b][i][j]*Kpt[b][k][j]) / sqrt(8)
// inputs pre-split bf16 hi/lo. 128x128 tiles, XCD-swizzled 1-D grid (256).
// =====================================================================
__global__ __launch_bounds__(256) void am_mfma2(
    const ushort* __restrict__ QH, const ushort* __restrict__ QL,
    const ushort* __restrict__ KH, const ushort* __restrict__ KL,
    float* __restrict__ am0) {
  int bid = blockIdx.x;
  int xcd = bid & 7, slot = bid >> 3;           // pin each batch's 16 tiles to one XCD
  int bz = xcd + 8 * (slot >> 4);
  int tt = slot & 15, ti = tt >> 2, tk = tt & 3;
  int bm0 = ti * 128, bn0 = tk * 128;
  size_t base = (size_t)bz * 262144;
  const ushort* AHp = QH + base + (size_t)bm0 * 512;
  const ushort* ALp = QL + base + (size_t)bm0 * 512;
  const ushort* BHp = KH + base + (size_t)bn0 * 512;
  const ushort* BLp = KL + base + (size_t)bn0 * 512;

  __shared__ __align__(16) char smem[40960];
  ushort (*Ah)[LDSTRIDE] = (ushort(*)[LDSTRIDE])(smem);
  ushort (*Al)[LDSTRIDE] = (ushort(*)[LDSTRIDE])(smem + 10240);
  ushort (*Bh)[LDSTRIDE] = (ushort(*)[LDSTRIDE])(smem + 20480);
  ushort (*Bl)[LDSTRIDE] = (ushort(*)[LDSTRIDE])(smem + 30720);

  int tid = threadIdx.x;
  int w = tid >> 6, lane = tid & 63, quad = lane >> 4, l16 = lane & 15;
  int wm = (w >> 1) * 64, wn = (w & 1) * 64;

  floatx4 acc[4][4] = {};

  for (int k0 = 0; k0 < 512; k0 += 32) {
    short8 ha[2], la[2], hb[2], lb[2];
#pragma unroll
    for (int g = 0; g < 2; ++g) {
      int gid = g * 256 + tid;
      int m = gid >> 2, kg = gid & 3;
      size_t off = (size_t)m * 512 + k0 + kg * 8;
      ha[g] = *(const short8*)(AHp + off);
      la[g] = *(const short8*)(ALp + off);
      hb[g] = *(const short8*)(BHp + off);
      lb[g] = *(const short8*)(BLp + off);
    }
    __syncthreads();
#pragma unroll
    for (int g = 0; g < 2; ++g) {
      int gid = g * 256 + tid;
      int m = gid >> 2, kg = gid & 3;
      *(short8*)&Ah[m][kg * 8] = ha[g];
      *(short8*)&Al[m][kg * 8] = la[g];
      *(short8*)&Bh[m][kg * 8] = hb[g];
      *(short8*)&Bl[m][kg * 8] = lb[g];
    }
    __syncthreads();
    short8 fAh[4], fAl[4], fBh[4], fBl[4];
#pragma unroll
    for (int t4 = 0; t4 < 4; ++t4) {
      int ma = wm + t4 * 16 + l16;
      int nb = wn + t4 * 16 + l16;
      fAh[t4] = *(const short8*)&Ah[ma][quad * 8];
      fAl[t4] = *(const short8*)&Al[ma][quad * 8];
      fBh[t4] = *(const short8*)&Bh[nb][quad * 8];
      fBl[t4] = *(const short8*)&Bl[nb][quad * 8];
    }
#pragma unroll
    for (int mt = 0; mt < 4; ++mt)
#pragma unroll
      for (int nt = 0; nt < 4; ++nt) {
        acc[mt][nt] = __builtin_amdgcn_mfma_f32_16x16x32_bf16(fAh[mt], fBh[nt], acc[mt][nt], 0, 0, 0);
        acc[mt][nt] = __builtin_amdgcn_mfma_f32_16x16x32_bf16(fAh[mt], fBl[nt], acc[mt][nt], 0, 0, 0);
        acc[mt][nt] = __builtin_amdgcn_mfma_f32_16x16x32_bf16(fAl[mt], fBh[nt], acc[mt][nt], 0, 0, 0);
      }
  }
  const float scale = 0.35355339059327373f;  // 1/sqrt(8)
#pragma unroll
  for (int mt = 0; mt < 4; ++mt)
#pragma unroll
    for (int nt = 0; nt < 4; ++nt)
#pragma unroll
      for (int rr = 0; rr < 4; ++rr) {
        int row = bm0 + wm + mt * 16 + quad * 4 + rr;
        int col = bn0 + wn + nt * 16 + l16;
        am0[((size_t)(bz * 512 + row)) * 512 + col] = acc[mt][nt][rr] * scale;
      }
}

// =====================================================================
// small_gemm: out[b][j0+j] += sum_{k chunk} X[b][k]*W[j0+j][k] (+bias at y==0)
// =====================================================================
__global__ __launch_bounds__(256) void small_gemm(
    const float* __restrict__ X, const float* __restrict__ W,
    const float* __restrict__ bias, float* __restrict__ out, int K) {
  __shared__ float xs[16 * 260];
  __shared__ float ws[16 * 260];
  int tid = threadIdx.x;
  int j0 = blockIdx.x * 16;
  int k0 = blockIdx.y * 256;
#pragma unroll
  for (int it = 0; it < 4; ++it) {
    int idx = it * 256 + tid;
    int rr = idx >> 6, kk4 = idx & 63;
    float4 xv = *(const float4*)(X + (size_t)rr * K + k0 + kk4 * 4);
    float4 wv = *(const float4*)(W + (size_t)(j0 + rr) * K + k0 + kk4 * 4);
    *(float4*)&xs[rr * 260 + kk4 * 4] = xv;
    *(float4*)&ws[rr * 260 + kk4 * 4] = wv;
  }
  __syncthreads();
  int b = tid & 15, j = tid >> 4;
  const float* xr = &xs[b * 260];
  const float* wr = &ws[j * 260];
  float acc = 0.f;
#pragma unroll
  for (int kk = 0; kk < 256; kk += 4) {
    float4 a = *(const float4*)(xr + kk);
    float4 w4 = *(const float4*)(wr + kk);
    acc += a.x * w4.x + a.y * w4.y + a.z * w4.z + a.w * w4.w;
  }
  if (blockIdx.y == 0) acc += bias[j0 + j];
  atomicAdd(&out[b * 512 + j0 + j], acc);
}

// ---------------- soft: wave-per-row (b,h,i), mutate variant ----------------
__global__ __launch_bounds__(256) void soft_mut(
    const float* __restrict__ am0, const float* __restrict__ Vp,
    float* __restrict__ oa, uint32_t km0, uint32_t km1) {
  int tid = threadIdx.x;
  int w = tid >> 6, lane = tid & 63;
  int rrow = blockIdx.x * 4 + w;
  int b = rrow >> 12, h = (rrow >> 9) & 7, i = rrow & 511;
  const float* ar = am0 + ((size_t)((b << 9) + i)) * A_;
  const float* vr = Vp + (b << 9);
  uint32_t Lb = ((uint32_t)(((b * 8 + h) << 9) + i)) << 9;
  float x[8], vv[8];
#pragma unroll
  for (int j = 0; j < 8; ++j) {
    int k = lane + 64 * j;
    float a = ar[k];
    vv[j] = vr[k];
    x[j] = a * mutval(km0, km1, Lb + (uint32_t)k);
  }
  // no max-subtraction: |x| <= ~16 so exp is fp32-safe; result identical ratio
  float s = 0.f, wsum = 0.f;
#pragma unroll
  for (int j = 0; j < 8; ++j) {
    float e = __expf(x[j]);
    s += e;
    wsum += e * vv[j];
  }
#pragma unroll
  for (int o = 32; o; o >>= 1) { s += __shfl_xor(s, o); wsum += __shfl_xor(wsum, o); }
  if (lane == 0) oa[(((size_t)(b * 8 + h)) << 9) + i] = wsum / s;
}

// ---------------- soft: crossover variant ----------------
struct CrossCfg { int r1[B_ * H_]; int r2[B_ * H_]; };

__global__ __launch_bounds__(256) void soft_cross(
    const float* __restrict__ am0, const float* __restrict__ Vp,
    float* __restrict__ oa, CrossCfg cfg) {
  int tid = threadIdx.x;
  int w = tid >> 6, lane = tid & 63;
  int rrow = blockIdx.x * 4 + w;
  int b = rrow >> 12, h = (rrow >> 9) & 7, i = rrow & 511;
  int rr1 = cfg.r1[b * 8 + h], rr2 = cfg.r2[b * 8 + h];
  int src = (i == rr2) ? rr1 : ((i == rr1) ? rr2 : i);
  const float* ar = am0 + ((size_t)((b << 9) + i)) * A_;
  const float* ar2 = am0 + ((size_t)((b << 9) + src)) * A_;
  const float* vr = Vp + (b << 9);
  float x[8], vv[8];
#pragma unroll
  for (int j = 0; j < 8; ++j) {
    int k = lane + 64 * j;
    vv[j] = vr[k];
    x[j] = (k >= C_CROSS) ? ar2[k] : ar[k];
  }
  float s = 0.f, wsum = 0.f;
#pragma unroll
  for (int j = 0; j < 8; ++j) {
    float e = __expf(x[j]);
    s += e;
    wsum += e * vv[j];
  }
#pragma unroll
  for (int o = 32; o; o >>= 1) { s += __shfl_xor(s, o); wsum += __shfl_xor(wsum, o); }
  if (lane == 0) oa[(((size_t)(b * 8 + h)) << 9) + i] = wsum / s;
}

extern "C" void kernel_launch(void* const* d_in, const int* in_sizes, int n_in,
                              void* d_out, int out_size, void* d_ws, size_t ws_size,
                              hipStream_t stream) {
  (void)in_sizes; (void)n_in; (void)out_size; (void)ws_size;
  const float* Q    = (const float*)d_in[0];
  const float* K    = (const float*)d_in[1];
  const float* V    = (const float*)d_in[2];
  const float* WQ_w = (const float*)d_in[3];
  const float* WQ_b = (const float*)d_in[4];
  const float* WK_w = (const float*)d_in[5];
  const float* WK_b = (const float*)d_in[6];
  const float* WV_w = (const float*)d_in[7];
  const float* WV_b = (const float*)d_in[8];
  const float* WO_w = (const float*)d_in[9];
  const float* WO_b = (const float*)d_in[10];
  float* out = (float*)d_out;

  // ws: QptH/QptL/KptH/KptL (4 x 8.39MB bf16) + am0 (16.78MB) + Vp + oa  = ~50.7MB
  char* ws = (char*)d_ws;
  ushort* QptH = (ushort*)(ws);
  ushort* QptL = (ushort*)(ws + (size_t)8388608);
  ushort* KptH = (ushort*)(ws + (size_t)16777216);
  ushort* KptL = (ushort*)(ws + (size_t)25165824);
  float*  am0  = (float*) (ws + (size_t)33554432);
  float*  Vp   = (float*) (ws + (size_t)50331648);
  float*  oa   = (float*) (ws + (size_t)50331648 + 65536);

  // ---- host-side deterministic RNG config (partitionable threefry) ----
  uint32_t kp0, kp1, km0, km1, kr10, kr11, kr20, kr21, a, bbits;
  tf2x32(0u, 42u, 0u, 0u, kp0, kp1);
  tf2x32(0u, 42u, 0u, 1u, km0, km1);
  tf2x32(0u, 42u, 0u, 2u, kr10, kr11);
  tf2x32(0u, 42u, 0u, 3u, kr20, kr21);
  tf2x32(kp0, kp1, 0u, 0u, a, bbits);
  float p = bits2u01(a ^ bbits);
  if (p < 0.f) p = 0.f;
  bool mutate = (p <= 0.6f);

  hipMemsetAsync(Vp, 0, 16 * 512 * sizeof(float), stream);
  hipMemsetAsync(out, 0, 16 * 512 * sizeof(float), stream);

  lin_mfma2<<<512, 256, 0, stream>>>(Q, WQ_w, WQ_b, QptH, QptL,
                                     K, WK_w, WK_b, KptH, KptL);
  small_gemm<<<dim3(32, 2), 256, 0, stream>>>(V, WV_w, WV_b, Vp, 512);
  am_mfma2<<<256, 256, 0, stream>>>(QptH, QptL, KptH, KptL, am0);
  if (mutate) {
    soft_mut<<<16384, 256, 0, stream>>>(am0, Vp, oa, km0, km1);
  } else {
    CrossCfg cfg;
    uint32_t c0, c1;
    tf2x32(kr10, kr11, 0u, 1u, c0, c1);
    for (int t = 0; t < B_ * H_; ++t) {
      tf2x32(c0, c1, 0u, (uint32_t)t, a, bbits);
      cfg.r1[t] = (int)((a ^ bbits) & 511u);
    }
    tf2x32(kr20, kr21, 0u, 1u, c0, c1);
    for (int t = 0; t < B_ * H_; ++t) {
      tf2x32(c0, c1, 0u, (uint32_t)t, a, bbits);
      cfg.r2[t] = (int)((a ^ bbits) & 511u);
    }
    soft_cross<<<16384, 256, 0, stream>>>(am0, Vp, oa, cfg);
  }
  small_gemm<<<dim3(32, 16), 256, 0, stream>>>(oa, WO_w, WO_b, out, 4096);
}

// Round 6
// 223.436 us; speedup vs baseline: 2.0265x; 1.1222x over previous
//
#include <hip/hip_runtime.h>
#include <stdint.h>
#include <string.h>

// B=16, A=512, H=8, c = 512 - int(512*0.3) = 359
#define B_ 16
#define A_ 512
#define H_ 8
#define C_CROSS 359
#define LDSTRIDE 40  // ushorts per 32-k LDS row (80 B, 16B-aligned, odd in 16B units)

typedef short short8 __attribute__((ext_vector_type(8)));
typedef float floatx4 __attribute__((ext_vector_type(4)));

// ---------------- threefry2x32 (exact JAX semantics, host+device) ----------------
__host__ __device__ __forceinline__ uint32_t rotl32(uint32_t x, int r) {
#ifdef __HIP_DEVICE_COMPILE__
  return __builtin_amdgcn_alignbit(x, x, 32 - r);
#else
  return (x << r) | (x >> (32 - r));
#endif
}

__host__ __device__ __forceinline__ void tf2x32(uint32_t k0, uint32_t k1,
                                                uint32_t x0, uint32_t x1,
                                                uint32_t& o0, uint32_t& o1) {
  uint32_t ks2 = k0 ^ k1 ^ 0x1BD11BDAu;
  x0 += k0; x1 += k1;
#define TFR(r) { x0 += x1; x1 = rotl32(x1, r); x1 ^= x0; }
  TFR(13) TFR(15) TFR(26) TFR(6)   x0 += k1;  x1 += ks2 + 1u;
  TFR(17) TFR(29) TFR(16) TFR(24)  x0 += ks2; x1 += k0 + 2u;
  TFR(13) TFR(15) TFR(26) TFR(6)   x0 += k0;  x1 += k1 + 3u;
  TFR(17) TFR(29) TFR(16) TFR(24)  x0 += k1;  x1 += ks2 + 4u;
  TFR(13) TFR(15) TFR(26) TFR(6)   x0 += ks2; x1 += k0 + 5u;
#undef TFR
  o0 = x0; o1 = x1;
}

__host__ __device__ __forceinline__ float bits2u01(uint32_t bits) {
  uint32_t v = (bits >> 9) | 0x3f800000u;
  float f;
#ifdef __HIP_DEVICE_COMPILE__
  f = __uint_as_float(v);
#else
  memcpy(&f, &v, 4);
#endif
  return f - 1.0f;
}

// ---------------- truncation-split bf16 helpers (4 instr/element) ----------------
__device__ __forceinline__ void tsplit(float x, short& h, short& l) {
  uint32_t u = __float_as_uint(x);
  float hf = __uint_as_float(u & 0xffff0000u);
  h = (short)(u >> 16);
  l = (short)(__float_as_uint(x - hf) >> 16);
}

__device__ __forceinline__ void tsplit8(const float4& v0, const float4& v1,
                                        short8& h, short8& l) {
  float xs[8] = {v0.x, v0.y, v0.z, v0.w, v1.x, v1.y, v1.z, v1.w};
#pragma unroll
  for (int j = 0; j < 8; ++j) {
    short hh, ll;
    tsplit(xs[j], hh, ll);
    h[j] = hh; l[j] = ll;
  }
}

// =====================================================================
// lin_mfma2: 128x128 tile, register double-buffered staging.
// C[m][d] = sum_l X[m][l]*W[d][l] + bias[d]; output TRANSPOSED, PRE-SPLIT:
//   OH/OL[(b*512 + d)*512 + i], m = b*512+i.  z = bid>>8 (0=Q,1=K).
// =====================================================================
__global__ __launch_bounds__(256, 2) void lin_mfma2(
    const float* __restrict__ Xq, const float* __restrict__ Wq,
    const float* __restrict__ bq, ushort* __restrict__ QptH, ushort* __restrict__ QptL,
    const float* __restrict__ Xk, const float* __restrict__ Wk,
    const float* __restrict__ bk, ushort* __restrict__ KptH, ushort* __restrict__ KptL) {
  int bid = blockIdx.x;
  int z = bid >> 8;
  int rem = bid & 255;
  int ti = rem >> 2, tn = rem & 3;
  const float* X = z ? Xk : Xq;
  const float* W = z ? Wk : Wq;
  const float* bias = z ? bk : bq;
  ushort* OH = z ? KptH : QptH;
  ushort* OL = z ? KptL : QptL;

  __shared__ __align__(16) char smem[40960];
  ushort (*Ah)[LDSTRIDE] = (ushort(*)[LDSTRIDE])(smem);
  ushort (*Al)[LDSTRIDE] = (ushort(*)[LDSTRIDE])(smem + 10240);
  ushort (*Bh)[LDSTRIDE] = (ushort(*)[LDSTRIDE])(smem + 20480);
  ushort (*Bl)[LDSTRIDE] = (ushort(*)[LDSTRIDE])(smem + 30720);
  uint32_t (*cs)[132] = (uint32_t(*)[132])(smem);  // epilogue alias

  int tid = threadIdx.x;
  int w = tid >> 6, lane = tid & 63, quad = lane >> 4, l16 = lane & 15;
  int wm = (w >> 1) * 64, wn = (w & 1) * 64;
  int m0 = ti * 128;  // global row (b*512+i)
  int n0 = tn * 128;  // d

  float bv[4];
#pragma unroll
  for (int nt = 0; nt < 4; ++nt) bv[nt] = bias[n0 + wn + nt * 16 + l16];

  // staging addresses: m = gid>>2 in [0,128), kg = gid&3
  const float* pX[2];
  const float* pW[2];
  int mW[2], kgW[2];
#pragma unroll
  for (int g = 0; g < 2; ++g) {
    int gid = g * 256 + tid;
    int m = gid >> 2, kg = gid & 3;
    mW[g] = m; kgW[g] = kg;
    pX[g] = X + (size_t)(m0 + m) * 512 + kg * 8;
    pW[g] = W + (size_t)(n0 + m) * 512 + kg * 8;
  }

  float4 ra[2][2], rb[2][2];
#pragma unroll
  for (int g = 0; g < 2; ++g) {
    ra[g][0] = *(const float4*)(pX[g]);
    ra[g][1] = *(const float4*)(pX[g] + 4);
    rb[g][0] = *(const float4*)(pW[g]);
    rb[g][1] = *(const float4*)(pW[g] + 4);
  }

  floatx4 acc[4][4] = {};

  for (int k0 = 0; k0 < 512; k0 += 32) {
    __syncthreads();
#pragma unroll
    for (int g = 0; g < 2; ++g) {
      short8 h8, l8;
      tsplit8(ra[g][0], ra[g][1], h8, l8);
      *(short8*)&Ah[mW[g]][kgW[g] * 8] = h8;
      *(short8*)&Al[mW[g]][kgW[g] * 8] = l8;
      tsplit8(rb[g][0], rb[g][1], h8, l8);
      *(short8*)&Bh[mW[g]][kgW[g] * 8] = h8;
      *(short8*)&Bl[mW[g]][kgW[g] * 8] = l8;
    }
    __syncthreads();
    if (k0 < 480) {
      int kn = k0 + 32;
#pragma unroll
      for (int g = 0; g < 2; ++g) {
        ra[g][0] = *(const float4*)(pX[g] + kn);
        ra[g][1] = *(const float4*)(pX[g] + kn + 4);
        rb[g][0] = *(const float4*)(pW[g] + kn);
        rb[g][1] = *(const float4*)(pW[g] + kn + 4);
      }
    }
    short8 fAh[4], fAl[4], fBh[4], fBl[4];
#pragma unroll
    for (int t4 = 0; t4 < 4; ++t4) {
      int ma = wm + t4 * 16 + l16;
      int nb = wn + t4 * 16 + l16;
      fAh[t4] = *(const short8*)&Ah[ma][quad * 8];
      fAl[t4] = *(const short8*)&Al[ma][quad * 8];
      fBh[t4] = *(const short8*)&Bh[nb][quad * 8];
      fBl[t4] = *(const short8*)&Bl[nb][quad * 8];
    }
#pragma unroll
    for (int mt = 0; mt < 4; ++mt)
#pragma unroll
      for (int nt = 0; nt < 4; ++nt) {
        acc[mt][nt] = __builtin_amdgcn_mfma_f32_16x16x32_bf16(fAh[mt], fBh[nt], acc[mt][nt], 0, 0, 0);
        acc[mt][nt] = __builtin_amdgcn_mfma_f32_16x16x32_bf16(fAh[mt], fBl[nt], acc[mt][nt], 0, 0, 0);
        acc[mt][nt] = __builtin_amdgcn_mfma_f32_16x16x32_bf16(fAl[mt], fBh[nt], acc[mt][nt], 0, 0, 0);
      }
  }

  // epilogue: +bias, truncation-split, transpose via LDS (two 64-col passes)
  __syncthreads();
  int bb = m0 >> 9, i0 = m0 & 511;
  for (int p = 0; p < 2; ++p) {
    if ((w & 1) == p) {
#pragma unroll
      for (int mt = 0; mt < 4; ++mt)
#pragma unroll
        for (int nt = 0; nt < 4; ++nt)
#pragma unroll
          for (int rr = 0; rr < 4; ++rr) {
            float val = acc[mt][nt][rr] + bv[nt];
            uint32_t u = __float_as_uint(val);
            uint32_t hi = u & 0xffff0000u;
            uint32_t lo = __float_as_uint(val - __uint_as_float(hi)) >> 16;
            cs[nt * 16 + l16][wm + mt * 16 + quad * 4 + rr] = hi | lo;
          }
    }
    __syncthreads();
    {
      int col_l = tid >> 2, iseg = (tid & 3) * 32;
      int d = n0 + p * 64 + col_l;
      size_t obase = ((size_t)(bb * 512 + d)) * 512 + i0 + iseg;
      ushort* oh = OH + obase;
      ushort* ol = OL + obase;
#pragma unroll
      for (int sgi = 0; sgi < 4; ++sgi) {
        short8 hv, lv;
#pragma unroll
        for (int j = 0; j < 8; ++j) {
          uint32_t v = cs[col_l][iseg + sgi * 8 + j];
          hv[j] = (short)(v >> 16);
          lv[j] = (short)(v & 0xffffu);
        }
        *(short8*)(oh + sgi * 8) = hv;
        *(short8*)(ol + sgi * 8) = lv;
      }
    }
    __syncthreads();
  }
}

// =====================================================================
// am_mfma2: am0[b][i][k] = (sum_j Qpt[b][i][j]*Kpt[b][k][j]) / sqrt(8)
// pre-split bf16 inputs, register double-buffered, XCD-swizzled grid (256).
// =====================================================================
__global__ __launch_bounds__(256, 2) void am_mfma2(
    const ushort* __restrict__ QH, const ushort* __restrict__ QL,
    const ushort* __restrict__ KH, const ushort* __restrict__ KL,
    float* __restrict__ am0) {
  int bid = blockIdx.x;
  int xcd = bid & 7, slot = bid >> 3;
  int bz = xcd + 8 * (slot >> 4);
  int tt = slot & 15, ti = tt >> 2, tk = tt & 3;
  int bm0 = ti * 128, bn0 = tk * 128;
  size_t base = (size_t)bz * 262144;

  __shared__ __align__(16) char smem[40960];
  ushort (*Ah)[LDSTRIDE] = (ushort(*)[LDSTRIDE])(smem);
  ushort (*Al)[LDSTRIDE] = (ushort(*)[LDSTRIDE])(smem + 10240);
  ushort (*Bh)[LDSTRIDE] = (ushort(*)[LDSTRIDE])(smem + 20480);
  ushort (*Bl)[LDSTRIDE] = (ushort(*)[LDSTRIDE])(smem + 30720);

  int tid = threadIdx.x;
  int w = tid >> 6, lane = tid & 63, quad = lane >> 4, l16 = lane & 15;
  int wm = (w >> 1) * 64, wn = (w & 1) * 64;

  const ushort *pAH[2], *pAL[2], *pBH[2], *pBL[2];
  int mW[2], kgW[2];
#pragma unroll
  for (int g = 0; g < 2; ++g) {
    int gid = g * 256 + tid;
    int m = gid >> 2, kg = gid & 3;
    mW[g] = m; kgW[g] = kg;
    size_t offA = base + (size_t)(bm0 + m) * 512 + kg * 8;
    size_t offB = base + (size_t)(bn0 + m) * 512 + kg * 8;
    pAH[g] = QH + offA; pAL[g] = QL + offA;
    pBH[g] = KH + offB; pBL[g] = KL + offB;
  }

  short8 rah[2], ral[2], rbh[2], rbl[2];
#pragma unroll
  for (int g = 0; g < 2; ++g) {
    rah[g] = *(const short8*)(pAH[g]);
    ral[g] = *(const short8*)(pAL[g]);
    rbh[g] = *(const short8*)(pBH[g]);
    rbl[g] = *(const short8*)(pBL[g]);
  }

  floatx4 acc[4][4] = {};

  for (int k0 = 0; k0 < 512; k0 += 32) {
    __syncthreads();
#pragma unroll
    for (int g = 0; g < 2; ++g) {
      *(short8*)&Ah[mW[g]][kgW[g] * 8] = rah[g];
      *(short8*)&Al[mW[g]][kgW[g] * 8] = ral[g];
      *(short8*)&Bh[mW[g]][kgW[g] * 8] = rbh[g];
      *(short8*)&Bl[mW[g]][kgW[g] * 8] = rbl[g];
    }
    __syncthreads();
    if (k0 < 480) {
      int kn = k0 + 32;
#pragma unroll
      for (int g = 0; g < 2; ++g) {
        rah[g] = *(const short8*)(pAH[g] + kn);
        ral[g] = *(const short8*)(pAL[g] + kn);
        rbh[g] = *(const short8*)(pBH[g] + kn);
        rbl[g] = *(const short8*)(pBL[g] + kn);
      }
    }
    short8 fAh[4], fAl[4], fBh[4], fBl[4];
#pragma unroll
    for (int t4 = 0; t4 < 4; ++t4) {
      int ma = wm + t4 * 16 + l16;
      int nb = wn + t4 * 16 + l16;
      fAh[t4] = *(const short8*)&Ah[ma][quad * 8];
      fAl[t4] = *(const short8*)&Al[ma][quad * 8];
      fBh[t4] = *(const short8*)&Bh[nb][quad * 8];
      fBl[t4] = *(const short8*)&Bl[nb][quad * 8];
    }
#pragma unroll
    for (int mt = 0; mt < 4; ++mt)
#pragma unroll
      for (int nt = 0; nt < 4; ++nt) {
        acc[mt][nt] = __builtin_amdgcn_mfma_f32_16x16x32_bf16(fAh[mt], fBh[nt], acc[mt][nt], 0, 0, 0);
        acc[mt][nt] = __builtin_amdgcn_mfma_f32_16x16x32_bf16(fAh[mt], fBl[nt], acc[mt][nt], 0, 0, 0);
        acc[mt][nt] = __builtin_amdgcn_mfma_f32_16x16x32_bf16(fAl[mt], fBh[nt], acc[mt][nt], 0, 0, 0);
      }
  }
  const float scale = 0.35355339059327373f;  // 1/sqrt(8)
#pragma unroll
  for (int mt = 0; mt < 4; ++mt)
#pragma unroll
    for (int nt = 0; nt < 4; ++nt)
#pragma unroll
      for (int rr = 0; rr < 4; ++rr) {
        int row = bm0 + wm + mt * 16 + quad * 4 + rr;
        int col = bn0 + wn + nt * 16 + l16;
        am0[((size_t)(bz * 512 + row)) * 512 + col] = acc[mt][nt][rr] * scale;
      }
}

// =====================================================================
// small_gemm: out[b][j0+j] += sum_{k chunk} X[b][k]*W[j0+j][k] (+bias at y==0)
// =====================================================================
__global__ __launch_bounds__(256) void small_gemm(
    const float* __restrict__ X, const float* __restrict__ W,
    const float* __restrict__ bias, float* __restrict__ out, int K) {
  __shared__ float xs[16 * 260];
  __shared__ float ws[16 * 260];
  int tid = threadIdx.x;
  int j0 = blockIdx.x * 16;
  int k0 = blockIdx.y * 256;
#pragma unroll
  for (int it = 0; it < 4; ++it) {
    int idx = it * 256 + tid;
    int rr = idx >> 6, kk4 = idx & 63;
    float4 xv = *(const float4*)(X + (size_t)rr * K + k0 + kk4 * 4);
    float4 wv = *(const float4*)(W + (size_t)(j0 + rr) * K + k0 + kk4 * 4);
    *(float4*)&xs[rr * 260 + kk4 * 4] = xv;
    *(float4*)&ws[rr * 260 + kk4 * 4] = wv;
  }
  __syncthreads();
  int b = tid & 15, j = tid >> 4;
  const float* xr = &xs[b * 260];
  const float* wr = &ws[j * 260];
  float acc = 0.f;
#pragma unroll
  for (int kk = 0; kk < 256; kk += 4) {
    float4 a = *(const float4*)(xr + kk);
    float4 w4 = *(const float4*)(wr + kk);
    acc += a.x * w4.x + a.y * w4.y + a.z * w4.z + a.w * w4.w;
  }
  if (blockIdx.y == 0) acc += bias[j0 + j];
  atomicAdd(&out[b * 512 + j0 + j], acc);
}

// ---------------- soft: wave-per-row (b,h,i), mutate; streaming, no arrays ----------------
__global__ __launch_bounds__(256) void soft_mut(
    const float* __restrict__ am0, const float* __restrict__ Vp,
    float* __restrict__ oa, uint32_t km0, uint32_t km1) {
  int tid = threadIdx.x;
  int w = tid >> 6, lane = tid & 63;
  int rrow = blockIdx.x * 4 + w;
  int b = rrow >> 12, h = (rrow >> 9) & 7, i = rrow & 511;
  const float* ar = am0 + ((size_t)((b << 9) + i)) * A_ + lane;
  const float* vr = Vp + (b << 9) + lane;
  uint32_t Lb = ((((uint32_t)(((b * 8 + h) << 9) + i)) << 9)) + (uint32_t)lane;
  float s = 0.f, wsum = 0.f;
#pragma unroll
  for (int j = 0; j < 8; ++j) {
    float a = ar[64 * j];
    float vv = vr[64 * j];
    uint32_t o0, o1;
    tf2x32(km0, km1, 0u, Lb + 64u * (uint32_t)j, o0, o1);
    uint32_t bits = o0 ^ o1;
    float f = __uint_as_float((bits >> 9) | 0x3f800000u);
    float m = fmaxf(0.7f, __builtin_fmaf(f, 0.6f, 0.1f));
    float e = __expf(a * m);
    s += e;
    wsum += e * vv;
  }
#pragma unroll
  for (int o = 32; o; o >>= 1) { s += __shfl_xor(s, o); wsum += __shfl_xor(wsum, o); }
  if (lane == 0) oa[(((size_t)(b * 8 + h)) << 9) + i] = wsum / s;
}

// ---------------- soft: crossover variant ----------------
struct CrossCfg { int r1[B_ * H_]; int r2[B_ * H_]; };

__global__ __launch_bounds__(256) void soft_cross(
    const float* __restrict__ am0, const float* __restrict__ Vp,
    float* __restrict__ oa, CrossCfg cfg) {
  int tid = threadIdx.x;
  int w = tid >> 6, lane = tid & 63;
  int rrow = blockIdx.x * 4 + w;
  int b = rrow >> 12, h = (rrow >> 9) & 7, i = rrow & 511;
  int rr1 = cfg.r1[b * 8 + h], rr2 = cfg.r2[b * 8 + h];
  int src = (i == rr2) ? rr1 : ((i == rr1) ? rr2 : i);
  const float* ar = am0 + ((size_t)((b << 9) + i)) * A_;
  const float* ar2 = am0 + ((size_t)((b << 9) + src)) * A_;
  const float* vr = Vp + (b << 9);
  float s = 0.f, wsum = 0.f;
#pragma unroll
  for (int j = 0; j < 8; ++j) {
    int k = lane + 64 * j;
    float x = (k >= C_CROSS) ? ar2[k] : ar[k];
    float e = __expf(x);
    s += e;
    wsum += e * vr[k];
  }
#pragma unroll
  for (int o = 32; o; o >>= 1) { s += __shfl_xor(s, o); wsum += __shfl_xor(wsum, o); }
  if (lane == 0) oa[(((size_t)(b * 8 + h)) << 9) + i] = wsum / s;
}

extern "C" void kernel_launch(void* const* d_in, const int* in_sizes, int n_in,
                              void* d_out, int out_size, void* d_ws, size_t ws_size,
                              hipStream_t stream) {
  (void)in_sizes; (void)n_in; (void)out_size; (void)ws_size;
  const float* Q    = (const float*)d_in[0];
  const float* K    = (const float*)d_in[1];
  const float* V    = (const float*)d_in[2];
  const float* WQ_w = (const float*)d_in[3];
  const float* WQ_b = (const float*)d_in[4];
  const float* WK_w = (const float*)d_in[5];
  const float* WK_b = (const float*)d_in[6];
  const float* WV_w = (const float*)d_in[7];
  const float* WV_b = (const float*)d_in[8];
  const float* WO_w = (const float*)d_in[9];
  const float* WO_b = (const float*)d_in[10];
  float* out = (float*)d_out;

  // ws: QptH/QptL/KptH/KptL (4 x 8.39MB bf16) + am0 (16.78MB) + Vp + oa ≈ 50.7MB
  char* ws = (char*)d_ws;
  ushort* QptH = (ushort*)(ws);
  ushort* QptL = (ushort*)(ws + (size_t)8388608);
  ushort* KptH = (ushort*)(ws + (size_t)16777216);
  ushort* KptL = (ushort*)(ws + (size_t)25165824);
  float*  am0  = (float*) (ws + (size_t)33554432);
  float*  Vp   = (float*) (ws + (size_t)50331648);
  float*  oa   = (float*) (ws + (size_t)50331648 + 65536);

  // ---- host-side deterministic RNG config (partitionable threefry) ----
  uint32_t kp0, kp1, km0, km1, kr10, kr11, kr20, kr21, a, bbits;
  tf2x32(0u, 42u, 0u, 0u, kp0, kp1);
  tf2x32(0u, 42u, 0u, 1u, km0, km1);
  tf2x32(0u, 42u, 0u, 2u, kr10, kr11);
  tf2x32(0u, 42u, 0u, 3u, kr20, kr21);
  tf2x32(kp0, kp1, 0u, 0u, a, bbits);
  float p = bits2u01(a ^ bbits);
  if (p < 0.f) p = 0.f;
  bool mutate = (p <= 0.6f);

  hipMemsetAsync(Vp, 0, 16 * 512 * sizeof(float), stream);
  hipMemsetAsync(out, 0, 16 * 512 * sizeof(float), stream);

  lin_mfma2<<<512, 256, 0, stream>>>(Q, WQ_w, WQ_b, QptH, QptL,
                                     K, WK_w, WK_b, KptH, KptL);
  small_gemm<<<dim3(32, 2), 256, 0, stream>>>(V, WV_w, WV_b, Vp, 512);
  am_mfma2<<<256, 256, 0, stream>>>(QptH, QptL, KptH, KptL, am0);
  if (mutate) {
    soft_mut<<<16384, 256, 0, stream>>>(am0, Vp, oa, km0, km1);
  } else {
    CrossCfg cfg;
    uint32_t c0, c1;
    tf2x32(kr10, kr11, 0u, 1u, c0, c1);
    for (int t = 0; t < B_ * H_; ++t) {
      tf2x32(c0, c1, 0u, (uint32_t)t, a, bbits);
      cfg.r1[t] = (int)((a ^ bbits) & 511u);
    }
    tf2x32(kr20, kr21, 0u, 1u, c0, c1);
    for (int t = 0; t < B_ * H_; ++t) {
      tf2x32(c0, c1, 0u, (uint32_t)t, a, bbits);
      cfg.r2[t] = (int)((a ^ bbits) & 511u);
    }
    soft_cross<<<16384, 256, 0, stream>>>(am0, Vp, oa, cfg);
  }
  small_gemm<<<dim3(32, 16), 256, 0, stream>>>(oa, WO_w, WO_b, out, 4096);
}